// Round 3
// baseline (4226.321 us; speedup 1.0000x reference)
//
#include <hip/hip_runtime.h>
#include <math.h>

#define NN_ 200000
#define EE_ 400000
#define HH  96
#define LL  6
#define BB  4096
#define SCAN_B 1024
#define NB_SCAN 196   // cdiv(200000, 1024)

typedef short s8v __attribute__((ext_vector_type(8)));
typedef float f4v __attribute__((ext_vector_type(4)));

static inline int cdiv(int a, int b) { return (a + b - 1) / b; }

__device__ __forceinline__ float sigmoidf_(float x) { return 1.0f / (1.0f + __expf(-x)); }
__device__ __forceinline__ float tanhf_(float x) { return 1.0f - 2.0f / (__expf(2.0f * x) + 1.0f); }
__device__ __forceinline__ unsigned short f2bf(float x) {
    unsigned u = __float_as_uint(x);
    unsigned r = u + 0x7FFF + ((u >> 16) & 1);   // RNE
    return (unsigned short)(r >> 16);
}
__device__ __forceinline__ float bf2f(unsigned short u) {
    return __uint_as_float(((unsigned)u) << 16);
}
// load 8 consecutive fp32 and convert to a bf16x8 MFMA fragment (in-register)
__device__ __forceinline__ s8v load_bf8(const float* __restrict__ p) {
    float4 v0 = *(const float4*)p;
    float4 v1 = *(const float4*)(p + 4);
    s8v r;
    r[0] = (short)f2bf(v0.x); r[1] = (short)f2bf(v0.y);
    r[2] = (short)f2bf(v0.z); r[3] = (short)f2bf(v0.w);
    r[4] = (short)f2bf(v1.x); r[5] = (short)f2bf(v1.y);
    r[6] = (short)f2bf(v1.z); r[7] = (short)f2bf(v1.w);
    return r;
}

// ---------------------------------------------------------------------------
// MLP weight pack (B-operand fragment order, read from global):
// Bp[((k>>5)*N + n)*32 + ((k>>3)&3)*8 + (k&7)] = bf16(B[k*N + n])
// ---------------------------------------------------------------------------
__global__ void packB_k(const float* __restrict__ B, unsigned short* __restrict__ Bp,
                        int K, int N)
{
    int idx = blockIdx.x * 256 + threadIdx.x;
    if (idx >= K * N) return;
    int k = idx / N, n = idx % N;
    Bp[(((size_t)(k >> 5) * N + n) * 4 + ((k >> 3) & 3)) * 8 + (k & 7)] = f2bf(B[idx]);
}

// ---------------------------------------------------------------------------
// Wp pack, weight-stationary A-operand order:
// offset = (((l*6 + jb)*3 + ks)*64 + lane)*8 + j
//   holds  W[l][k = ks*32 + (lane>>4)*8 + j][n = jb*16 + (lane&15)]
// ---------------------------------------------------------------------------
__global__ void packWp_k(const float* __restrict__ W, unsigned short* __restrict__ Wp)
{
    int idx = blockIdx.x * 256 + threadIdx.x;
    if (idx >= LL * 6 * 3 * 64 * 8) return;
    int j    = idx & 7;
    int lane = (idx >> 3) & 63;
    int rest = idx >> 9;
    int ks = rest % 3;
    int jb = (rest / 3) % 6;
    int l  = rest / 18;
    int quad = lane >> 4, lc = lane & 15;
    int k = ks * 32 + quad * 8 + j;
    int n = jb * 16 + lc;
    Wp[idx] = f2bf(W[(size_t)l * 9216 + (size_t)k * 96 + n]);
}

// ---------------------------------------------------------------------------
// Wgp pack, weight-stationary A-operand order, gate-interleaved:
// T = jb*4 + g;  offset = ((T*6 + ks)*64 + lane)*8 + j
//   holds  Wg[k = ks*32 + quad*8 + j][n = g*96 + jb*16 + lc]
// Wg semantics: k<96 from wih (agg side), k>=96 from whh (h side);
// n in [0,192): r/z sums; [192,288): i_n (wih only); [288,384): h_n (whh only)
// ---------------------------------------------------------------------------
__global__ void packWgp_k(const float* __restrict__ wih, const float* __restrict__ whh,
                          unsigned short* __restrict__ Wgp)
{
    int idx = blockIdx.x * 256 + threadIdx.x;
    if (idx >= 24 * 6 * 64 * 8) return;
    int j    = idx & 7;
    int lane = (idx >> 3) & 63;
    int rest = idx >> 9;
    int ks = rest % 6;
    int T  = rest / 6;
    int quad = lane >> 4, lc = lane & 15;
    int g = T & 3, jb = T >> 2;
    int k = ks * 32 + quad * 8 + j;
    int n = g * 96 + jb * 16 + lc;
    float v;
    if (n < 192) {
        v = (k < 96) ? wih[(size_t)n * 96 + k] : whh[(size_t)n * 96 + (k - 96)];
    } else if (n < 288) {
        int jj = n - 192;
        v = (k < 96) ? wih[(size_t)(192 + jj) * 96 + k] : 0.f;
    } else {
        int jj = n - 288;
        v = (k < 96) ? 0.f : whh[(size_t)(192 + jj) * 96 + (k - 96)];
    }
    Wgp[idx] = f2bf(v);
}

// combined bias pack: bs[0..95]=bih_r+bhh_r, [96..191]=bih_z+bhh_z,
// [192..287]=bih_n, [288..383]=bhh_n
__global__ void bpack_k(const float* __restrict__ bih, const float* __restrict__ bhh,
                        float* __restrict__ bs)
{
    int j = threadIdx.x;
    if (j >= 96) return;
    bs[j]        = bih[j] + bhh[j];
    bs[96 + j]   = bih[96 + j] + bhh[96 + j];
    bs[192 + j]  = bih[192 + j];
    bs[288 + j]  = bhh[192 + j];
}

__global__ void pad_k(const float* __restrict__ x, float* __restrict__ h)
{
    int idx = blockIdx.x * 256 + threadIdx.x;
    if (idx >= NN_ * HH) return;
    int n = idx / HH, j = idx % HH;
    h[idx] = (j < 32) ? x[n * 32 + j] : 0.f;
}

// --------------------------- CSR build (once per component) -----------------
__global__ void deg_k(const int* __restrict__ ei, int* __restrict__ deg)
{
    int e = blockIdx.x * 256 + threadIdx.x;
    if (e >= EE_) return;
    atomicAdd(&deg[ei[EE_ + e]], 1);
}

__global__ __launch_bounds__(SCAN_B) void scan1_k(
    const int* __restrict__ deg, int* __restrict__ rp, int* __restrict__ bsum)
{
    __shared__ int sh[SCAN_B];
    int i = blockIdx.x * SCAN_B + threadIdx.x;
    int v = (i < NN_) ? deg[i] : 0;
    sh[threadIdx.x] = v;
    __syncthreads();
    for (int off = 1; off < SCAN_B; off <<= 1) {
        int t = (threadIdx.x >= off) ? sh[threadIdx.x - off] : 0;
        __syncthreads();
        sh[threadIdx.x] += t;
        __syncthreads();
    }
    if (i < NN_) rp[i] = sh[threadIdx.x] - v;     // exclusive within block
    if (threadIdx.x == SCAN_B - 1) bsum[blockIdx.x] = sh[threadIdx.x];
}

__global__ __launch_bounds__(256) void scan2_k(int* __restrict__ bsum)
{
    __shared__ int sh[256];
    int v = (threadIdx.x < NB_SCAN) ? bsum[threadIdx.x] : 0;
    sh[threadIdx.x] = v;
    __syncthreads();
    for (int off = 1; off < 256; off <<= 1) {
        int t = (threadIdx.x >= off) ? sh[threadIdx.x - off] : 0;
        __syncthreads();
        sh[threadIdx.x] += t;
        __syncthreads();
    }
    if (threadIdx.x < NB_SCAN) bsum[threadIdx.x] = sh[threadIdx.x] - v;  // exclusive
}

__global__ void scan3_k(int* __restrict__ rp, const int* __restrict__ bsum,
                        int* __restrict__ cur)
{
    int i = blockIdx.x * 256 + threadIdx.x;
    if (i < NN_) {
        int r = rp[i] + bsum[i / SCAN_B];
        rp[i] = r;
        cur[i] = r;
    }
    if (i == 0) rp[NN_] = EE_;
}

// srcs stores BYTE offsets into the fp32 h rows (s * 384).
__global__ void fill_k(const int* __restrict__ ei, int* __restrict__ cur,
                       int* __restrict__ srcs)
{
    int e = blockIdx.x * 256 + threadIdx.x;
    if (e >= EE_) return;
    int s = ei[e];
    int d = ei[EE_ + e];
    int pos = atomicAdd(&cur[d], 1);
    srcs[pos] = s * 384;
}

// batch row pointers: batch[] is sorted, detect segment boundaries.
__global__ void brp_k(const int* __restrict__ bat, int* __restrict__ rpb)
{
    int i = blockIdx.x * 256 + threadIdx.x;
    if (i >= NN_) return;
    int b = bat[i];
    if (i == 0) {
        for (int q = 0; q <= b; q++) rpb[q] = 0;
    } else {
        int p = bat[i - 1];
        for (int q = p + 1; q <= b; q++) rpb[q] = i;
    }
    if (i == NN_ - 1) {
        for (int q = b + 1; q <= BB; q++) rpb[q] = NN_;
    }
}

// ---------------------------------------------------------------------------
// Fully fused GGC layer (ONE dispatch per layer). Uses linearity:
//   agg = sum_src(h W) = (sum_src h) W.
// v3: SINGLE fp32 state, ping-pong (hp -> hn). No bf16 shadow copy: per-layer
// HBM traffic drops from ~272 MB (fp32 h R/W + bf16 hbf R/W) to ~160 MB.
// Gather accumulates raw fp32 rows (no unpack VALU); all MFMA operands are
// converted to bf16 in-register.
// Block = 128 thr (2 waves); wave owns 32 nodes (2 tiles of 16) exclusively.
// No barriers (LDS traffic wave-local); hp/hn distinct so cross-block gathers
// only see prev-layer values.
// ---------------------------------------------------------------------------
__global__ __launch_bounds__(128) void layer_k(
    const int* __restrict__ rp, const int* __restrict__ srcs,
    const float* __restrict__ hp,            // prev-layer h (read-only)
    const unsigned short* __restrict__ Wp,   // this layer: [6][3][64][8]
    const unsigned short* __restrict__ Wgp,  // [24][6][64][8]
    const float* __restrict__ bs,
    float* __restrict__ hn)                  // next-layer h (write-only)
{
    __shared__ unsigned short as_[2][32][104];   // 13,312 B; [wave][node][feat+pad]
    int tid  = threadIdx.x;
    int wave = tid >> 6;
    int lane = tid & 63;
    int quad = lane >> 4;
    int lc   = lane & 15;
    int nT0  = blockIdx.x * 4 + wave * 2;        // node-tile base (16 nodes/tile)

    // hoist CSR range loads
    int n0 = nT0 * 16 + lc;
    int e0t[2], e1t[2];
    e0t[0] = rp[n0];      e1t[0] = rp[n0 + 1];
    e0t[1] = rp[n0 + 16]; e1t[1] = rp[n0 + 17];

    // lane's feature slice within a row: bytes ks*128 + quad*32 .. +32
    const char* gbase = (const char*)hp + quad * 32;

    // ---- Stage 0: gather hagg = sum over in-edges of hp (fp32) ----
    s8v hg[2][3];
    #pragma unroll
    for (int t = 0; t < 2; t++) {
        float ag[24];
        #pragma unroll
        for (int i = 0; i < 24; i++) ag[i] = 0.f;
        int e = e0t[t], e1 = e1t[t];
        for (; e < e1; e++) {
            const char* r = gbase + srcs[e];
            float4 a0 = *(const float4*)(r);
            float4 a1 = *(const float4*)(r + 16);
            float4 a2 = *(const float4*)(r + 128);
            float4 a3 = *(const float4*)(r + 144);
            float4 a4 = *(const float4*)(r + 256);
            float4 a5 = *(const float4*)(r + 272);
            ag[0]  += a0.x; ag[1]  += a0.y; ag[2]  += a0.z; ag[3]  += a0.w;
            ag[4]  += a1.x; ag[5]  += a1.y; ag[6]  += a1.z; ag[7]  += a1.w;
            ag[8]  += a2.x; ag[9]  += a2.y; ag[10] += a2.z; ag[11] += a2.w;
            ag[12] += a3.x; ag[13] += a3.y; ag[14] += a3.z; ag[15] += a3.w;
            ag[16] += a4.x; ag[17] += a4.y; ag[18] += a4.z; ag[19] += a4.w;
            ag[20] += a5.x; ag[21] += a5.y; ag[22] += a5.z; ag[23] += a5.w;
        }
        #pragma unroll
        for (int ks = 0; ks < 3; ks++) {
            s8v v;
            #pragma unroll
            for (int j = 0; j < 8; j++) v[j] = (short)f2bf(ag[ks * 8 + j]);
            hg[t][ks] = v;
        }
    }

    // hoist own-row h fragments (fp32 -> bf16); latency hides under Stage-1
    s8v dh[2][3];
    #pragma unroll
    for (int t = 0; t < 2; t++) {
        int node = (nT0 + t) * 16 + lc;
        #pragma unroll
        for (int ks = 0; ks < 3; ks++)
            dh[t][ks] = load_bf8(hp + (size_t)node * 96 + ks * 32 + quad * 8);
    }

    // ---- Stage 1: agg = hagg @ W -> LDS transpose (bf16) ----
    for (int jb = 0; jb < 6; jb++) {
        f4v a1[2] = {};
        #pragma unroll
        for (int ks = 0; ks < 3; ks++) {
            s8v w = *(const s8v*)(Wp + ((size_t)(jb * 3 + ks) * 64 + lane) * 8);
            a1[0] = __builtin_amdgcn_mfma_f32_16x16x32_bf16(w, hg[0][ks], a1[0], 0, 0, 0);
            a1[1] = __builtin_amdgcn_mfma_f32_16x16x32_bf16(w, hg[1][ks], a1[1], 0, 0, 0);
        }
        #pragma unroll
        for (int t = 0; t < 2; t++) {
            unsigned short o0 = f2bf(a1[t][0]), o1 = f2bf(a1[t][1]);
            unsigned short o2 = f2bf(a1[t][2]), o3 = f2bf(a1[t][3]);
            *(uint2*)&as_[wave][t * 16 + lc][jb * 16 + quad * 4] =
                make_uint2((unsigned)o0 | ((unsigned)o1 << 16),
                           (unsigned)o2 | ((unsigned)o3 << 16));
        }
    }

    // ---- Stage 2: data fragments for the G-GEMM ----
    s8v d[2][6];
    #pragma unroll
    for (int t = 0; t < 2; t++) {
        #pragma unroll
        for (int ks = 0; ks < 3; ks++)
            d[t][ks] = *(const s8v*)&as_[wave][t * 16 + lc][ks * 32 + quad * 8];
        #pragma unroll
        for (int ks = 0; ks < 3; ks++)
            d[t][3 + ks] = dh[t][ks];
    }

    // ---- Stage 3: G-GEMM + GRUCell epilogue ----
    for (int jb = 0; jb < 6; jb++) {
        // prefetch h_old (independent of MFMAs below)
        float4 hold[2];
        #pragma unroll
        for (int t = 0; t < 2; t++)
            hold[t] = *(const float4*)(hp + (size_t)((nT0 + t) * 16 + lc) * 96 + jb * 16 + quad * 4);
        f4v acc[2][4] = {};
        #pragma unroll
        for (int g = 0; g < 4; g++) {
            const unsigned short* wb = Wgp + (size_t)(jb * 4 + g) * 6 * 64 * 8;
            #pragma unroll
            for (int ks = 0; ks < 6; ks++) {
                s8v w = *(const s8v*)(wb + ((size_t)ks * 64 + lane) * 8);
                acc[0][g] = __builtin_amdgcn_mfma_f32_16x16x32_bf16(w, d[0][ks], acc[0][g], 0, 0, 0);
                acc[1][g] = __builtin_amdgcn_mfma_f32_16x16x32_bf16(w, d[1][ks], acc[1][g], 0, 0, 0);
            }
        }
        const float* bp = bs + jb * 16 + quad * 4;
        float4 br  = *(const float4*)(bp);
        float4 bz  = *(const float4*)(bp + 96);
        float4 bin = *(const float4*)(bp + 192);
        float4 bhn = *(const float4*)(bp + 288);
        float brv[4]  = {br.x, br.y, br.z, br.w};
        float bzv[4]  = {bz.x, bz.y, bz.z, bz.w};
        float binv[4] = {bin.x, bin.y, bin.z, bin.w};
        float bhnv[4] = {bhn.x, bhn.y, bhn.z, bhn.w};
        #pragma unroll
        for (int t = 0; t < 2; t++) {
            int node = (nT0 + t) * 16 + lc;
            float hv[4] = {hold[t].x, hold[t].y, hold[t].z, hold[t].w};
            float out[4];
            #pragma unroll
            for (int i = 0; i < 4; i++) {
                float rg = sigmoidf_(acc[t][0][i] + brv[i]);
                float zg = sigmoidf_(acc[t][1][i] + bzv[i]);
                float nn = tanhf_(acc[t][2][i] + binv[i] + rg * (acc[t][3][i] + bhnv[i]));
                out[i] = (1.f - zg) * nn + zg * hv[i];
            }
            float* hq = hn + (size_t)node * 96 + jb * 16 + quad * 4;
            *(float4*)hq = make_float4(out[0], out[1], out[2], out[3]);
        }
    }
}

// ---------------------------------------------------------------------------
// Mean pool via sorted-batch segments: one block per graph, no atomics.
// ---------------------------------------------------------------------------
__global__ __launch_bounds__(128) void pool_csr_k(
    const float* __restrict__ h, const int* __restrict__ rpb, float* __restrict__ g)
{
    int b = blockIdx.x;
    int j = threadIdx.x;
    if (j >= 96) return;
    int n0 = rpb[b], n1 = rpb[b + 1];
    float s = 0.f;
    for (int n = n0; n < n1; n++) s += fmaxf(h[(size_t)n * 96 + j], 0.f);
    float c = (float)(n1 - n0);
    g[(size_t)b * 96 + j] = s / fmaxf(c, 1.f);
}

__global__ void feat_k(const float* __restrict__ g1, const float* __restrict__ g2,
                       const float* __restrict__ g3, float* __restrict__ feat)
{
    int idx = blockIdx.x * 256 + threadIdx.x;
    if (idx >= BB * HH) return;
    int b = idx / HH, j = idx % HH;
    float a = g1[idx], bb = g2[idx], c = g3[idx];
    float* f = feat + (size_t)b * 384;
    f[j]       = a;
    f[96 + j]  = bb;
    f[192 + j] = c;
    f[288 + j] = a * bb * c;
}

// ---------------------------------------------------------------------------
// MLP GEMM: C[M,N] = relu(bf16(A[M,K]) @ Bp + bias).
// ---------------------------------------------------------------------------
__global__ __launch_bounds__(256) void gemm_mlp_mfma(
    const float* __restrict__ A, const unsigned short* __restrict__ Bp,
    const float* __restrict__ bias, float* __restrict__ C,
    int K, int N, int doRelu)
{
    int wave = threadIdx.x >> 6;
    int lane = threadIdx.x & 63;
    int quad = lane >> 4;
    int lc   = lane & 15;
    int rowA = blockIdx.y * 64 + wave * 16 + lc;
    int colb = blockIdx.x * 128;

    f4v acc[8] = {};
    for (int ks = 0; ks < K / 32; ks++) {
        s8v a = load_bf8(A + (size_t)rowA * K + ks * 32 + quad * 8);
        #pragma unroll
        for (int t = 0; t < 8; t++) {
            int n = colb + t * 16 + lc;
            s8v b = *(const s8v*)(Bp + ((size_t)(ks * N + n) * 4 + quad) * 8);
            acc[t] = __builtin_amdgcn_mfma_f32_16x16x32_bf16(a, b, acc[t], 0, 0, 0);
        }
    }
    int rowD = blockIdx.y * 64 + wave * 16 + quad * 4;
    #pragma unroll
    for (int t = 0; t < 8; t++) {
        int n = colb + t * 16 + lc;
        float bv = bias[n];
        #pragma unroll
        for (int r = 0; r < 4; r++) {
            float v = acc[t][r] + bv;
            if (doRelu) v = fmaxf(v, 0.f);
            C[(size_t)(rowD + r) * N + n] = v;
        }
    }
}

// fc3: one wave per graph, shuffle reduction.
__global__ __launch_bounds__(256) void fc3_k(const float* __restrict__ t2,
                                             const float* __restrict__ w,
                                             const float* __restrict__ bias,
                                             float* __restrict__ out)
{
    int wave = threadIdx.x >> 6;
    int lane = threadIdx.x & 63;
    int b = blockIdx.x * 4 + wave;
    const float* row = t2 + (size_t)b * 384;
    float a0 = 0.f, a1 = 0.f, a2 = 0.f;
    #pragma unroll
    for (int kk = 0; kk < 6; kk++) {
        int k = kk * 64 + lane;
        float x = row[k];
        a0 += x * w[k * 3 + 0];
        a1 += x * w[k * 3 + 1];
        a2 += x * w[k * 3 + 2];
    }
    #pragma unroll
    for (int off = 32; off > 0; off >>= 1) {
        a0 += __shfl_down(a0, off);
        a1 += __shfl_down(a1, off);
        a2 += __shfl_down(a2, off);
    }
    if (lane == 0) {
        out[b * 3 + 0] = a0 + bias[0];
        out[b * 3 + 1] = a1 + bias[1];
        out[b * 3 + 2] = a2 + bias[2];
    }
}

extern "C" void kernel_launch(void* const* d_in, const int* in_sizes, int n_in,
                              void* d_out, int out_size, void* d_ws, size_t ws_size,
                              hipStream_t stream)
{
    // Workspace (floats). Total ~41.2M f ≈ 165 MB (237 MB proven safe).
    float* ws    = (float*)d_ws;
    float* hA    = ws;                               // 19,200,000
    float* hB    = hA + (size_t)NN_ * HH;            // 19,200,000
    float* wpF   = hB + (size_t)NN_ * HH;            //     27,648
    float* wgpF  = wpF + 27648;                      //     36,864
    float* fc1pF = wgpF + 36864;                     //    294,912 (589,824 bf16)
    float* fc2pF = fc1pF + 294912;                   //    294,912
    float* g3    = fc2pF + 294912;                   //  1,179,648
    int*   rp    = (int*)(g3 + 3 * (size_t)BB * HH); //    200,064 ints
    int*   srcs  = rp + 200064;                      //    400,000 ints
    int*   deg   = srcs + 400000;                    //    200,000 ints
    int*   cur   = deg + 200000;                     //    200,000 ints
    int*   bsum  = cur + 200000;                     //        256 ints
    int*   rpb   = bsum + 256;                       //      4,097 ints
    float* bs    = (float*)(rpb + 4097) + 1;         //        384 f (16B-aligned region)

    unsigned short* Wp   = (unsigned short*)wpF;
    unsigned short* Wgp  = (unsigned short*)wgpF;
    unsigned short* fc1p = (unsigned short*)fc1pF;
    unsigned short* fc2p = (unsigned short*)fc2pF;

    // MLP temps alias hA (dead after pooling of all components)
    float* feat = hA;
    float* t1   = hA + 2 * 1024 * 1024;
    float* t2   = hA + 9 * 1024 * 1024;

    for (int c = 0; c < 3; c++) {
        const float* x   = (const float*)d_in[c * 8 + 0];
        const int*   ei  = (const int*)  d_in[c * 8 + 1];
        const int*   bat = (const int*)  d_in[c * 8 + 2];
        const float* W   = (const float*)d_in[c * 8 + 3];
        const float* wih = (const float*)d_in[c * 8 + 4];
        const float* whh = (const float*)d_in[c * 8 + 5];
        const float* bih = (const float*)d_in[c * 8 + 6];
        const float* bhh = (const float*)d_in[c * 8 + 7];

        // CSR build (once per component, reused for all 6 layers)
        hipMemsetAsync(deg, 0, NN_ * sizeof(int), stream);
        deg_k<<<cdiv(EE_, 256), 256, 0, stream>>>(ei, deg);
        scan1_k<<<NB_SCAN, SCAN_B, 0, stream>>>(deg, rp, bsum);
        scan2_k<<<1, 256, 0, stream>>>(bsum);
        scan3_k<<<cdiv(NN_, 256), 256, 0, stream>>>(rp, bsum, cur);
        fill_k<<<cdiv(EE_, 256), 256, 0, stream>>>(ei, cur, srcs);
        brp_k<<<cdiv(NN_, 256), 256, 0, stream>>>(bat, rpb);

        packWp_k<<<cdiv(LL * 6 * 3 * 64 * 8, 256), 256, 0, stream>>>(W, Wp);
        packWgp_k<<<cdiv(24 * 6 * 64 * 8, 256), 256, 0, stream>>>(wih, whh, Wgp);
        bpack_k<<<1, 128, 0, stream>>>(bih, bhh, bs);
        pad_k<<<cdiv(NN_ * HH, 256), 256, 0, stream>>>(x, hA);

        float* pb[2] = {hA, hB};
        for (int l = 0; l < LL; l++) {
            layer_k<<<NN_ / 64, 128, 0, stream>>>(
                rp, srcs, pb[l & 1], Wp + (size_t)l * 9216, Wgp, bs, pb[(l + 1) & 1]);
        }

        // LL=6 even -> final state is back in hA
        pool_csr_k<<<BB, 128, 0, stream>>>(hA, rpb, g3 + (size_t)c * BB * HH);
    }

    const float* fc1_w = (const float*)d_in[24];
    const float* fc1_b = (const float*)d_in[25];
    const float* fc2_w = (const float*)d_in[26];
    const float* fc2_b = (const float*)d_in[27];
    const float* fc3_w = (const float*)d_in[28];
    const float* fc3_b = (const float*)d_in[29];

    packB_k<<<cdiv(384 * 1536, 256), 256, 0, stream>>>(fc1_w, fc1p, 384, 1536);
    packB_k<<<cdiv(1536 * 384, 256), 256, 0, stream>>>(fc2_w, fc2p, 1536, 384);

    feat_k<<<cdiv(BB * HH, 256), 256, 0, stream>>>(
        g3, g3 + (size_t)BB * HH, g3 + 2 * (size_t)BB * HH, feat);
    gemm_mlp_mfma<<<dim3(1536 / 128, BB / 64), 256, 0, stream>>>(
        feat, fc1p, fc1_b, t1, 384, 1536, 1);
    gemm_mlp_mfma<<<dim3(384 / 128, BB / 64), 256, 0, stream>>>(
        t1, fc2p, fc2_b, t2, 1536, 384, 1);
    fc3_k<<<BB / 4, 256, 0, stream>>>(t2, fc3_w, fc3_b, (float*)d_out);
}

// Round 4
// 3927.321 us; speedup vs baseline: 1.0761x; 1.0761x over previous
//
#include <hip/hip_runtime.h>
#include <math.h>

#define NN_ 200000
#define EE_ 400000
#define HH  96
#define LL  6
#define BB  4096
#define SCAN_B 1024
#define NB_SCAN 196   // cdiv(200000, 1024)

typedef short s8v __attribute__((ext_vector_type(8)));
typedef float f4v __attribute__((ext_vector_type(4)));
typedef float f2v __attribute__((ext_vector_type(2)));

static inline int cdiv(int a, int b) { return (a + b - 1) / b; }

__device__ __forceinline__ float sigmoidf_(float x) { return 1.0f / (1.0f + __expf(-x)); }
__device__ __forceinline__ float tanhf_(float x) { return 1.0f - 2.0f / (__expf(2.0f * x) + 1.0f); }
__device__ __forceinline__ unsigned short f2bf(float x) {
    unsigned u = __float_as_uint(x);
    unsigned r = u + 0x7FFF + ((u >> 16) & 1);   // RNE
    return (unsigned short)(r >> 16);
}
__device__ __forceinline__ float bf2f(unsigned short u) {
    return __uint_as_float(((unsigned)u) << 16);
}
// load 8 consecutive fp32 and convert to a bf16x8 MFMA fragment (in-register)
__device__ __forceinline__ s8v load_bf8(const float* __restrict__ p) {
    float4 v0 = *(const float4*)p;
    float4 v1 = *(const float4*)(p + 4);
    s8v r;
    r[0] = (short)f2bf(v0.x); r[1] = (short)f2bf(v0.y);
    r[2] = (short)f2bf(v0.z); r[3] = (short)f2bf(v0.w);
    r[4] = (short)f2bf(v1.x); r[5] = (short)f2bf(v1.y);
    r[6] = (short)f2bf(v1.z); r[7] = (short)f2bf(v1.w);
    return r;
}

// bf16-pair accumulate: u holds 2 bf16; low elem -> a[0], high elem -> a[1]
__device__ __forceinline__ void accu_(f2v& a, unsigned u) {
    a[0] += __uint_as_float(u << 16);
    a[1] += __uint_as_float(u & 0xFFFF0000u);
}
__device__ __forceinline__ void acc_row_(f2v* ag2, const uint4& u, int ks) {
    accu_(ag2[ks * 4 + 0], u.x); accu_(ag2[ks * 4 + 1], u.y);
    accu_(ag2[ks * 4 + 2], u.z); accu_(ag2[ks * 4 + 3], u.w);
}

// ---------------------------------------------------------------------------
// MLP weight pack (B-operand fragment order, read from global):
// Bp[((k>>5)*N + n)*32 + ((k>>3)&3)*8 + (k&7)] = bf16(B[k*N + n])
// ---------------------------------------------------------------------------
__global__ void packB_k(const float* __restrict__ B, unsigned short* __restrict__ Bp,
                        int K, int N)
{
    int idx = blockIdx.x * 256 + threadIdx.x;
    if (idx >= K * N) return;
    int k = idx / N, n = idx % N;
    Bp[(((size_t)(k >> 5) * N + n) * 4 + ((k >> 3) & 3)) * 8 + (k & 7)] = f2bf(B[idx]);
}

// ---------------------------------------------------------------------------
// Wp pack, weight-stationary A-operand order:
// offset = (((l*6 + jb)*3 + ks)*64 + lane)*8 + j
//   holds  W[l][k = ks*32 + (lane>>4)*8 + j][n = jb*16 + (lane&15)]
// ---------------------------------------------------------------------------
__global__ void packWp_k(const float* __restrict__ W, unsigned short* __restrict__ Wp)
{
    int idx = blockIdx.x * 256 + threadIdx.x;
    if (idx >= LL * 6 * 3 * 64 * 8) return;
    int j    = idx & 7;
    int lane = (idx >> 3) & 63;
    int rest = idx >> 9;
    int ks = rest % 3;
    int jb = (rest / 3) % 6;
    int l  = rest / 18;
    int quad = lane >> 4, lc = lane & 15;
    int k = ks * 32 + quad * 8 + j;
    int n = jb * 16 + lc;
    Wp[idx] = f2bf(W[(size_t)l * 9216 + (size_t)k * 96 + n]);
}

// ---------------------------------------------------------------------------
// Wgp pack, weight-stationary A-operand order, gate-interleaved:
// T = jb*4 + g;  offset = ((T*6 + ks)*64 + lane)*8 + j
//   holds  Wg[k = ks*32 + quad*8 + j][n = g*96 + jb*16 + lc]
// Wg semantics: k<96 from wih (agg side), k>=96 from whh (h side);
// n in [0,192): r/z sums; [192,288): i_n (wih only); [288,384): h_n (whh only)
// ---------------------------------------------------------------------------
__global__ void packWgp_k(const float* __restrict__ wih, const float* __restrict__ whh,
                          unsigned short* __restrict__ Wgp)
{
    int idx = blockIdx.x * 256 + threadIdx.x;
    if (idx >= 24 * 6 * 64 * 8) return;
    int j    = idx & 7;
    int lane = (idx >> 3) & 63;
    int rest = idx >> 9;
    int ks = rest % 6;
    int T  = rest / 6;
    int quad = lane >> 4, lc = lane & 15;
    int g = T & 3, jb = T >> 2;
    int k = ks * 32 + quad * 8 + j;
    int n = g * 96 + jb * 16 + lc;
    float v;
    if (n < 192) {
        v = (k < 96) ? wih[(size_t)n * 96 + k] : whh[(size_t)n * 96 + (k - 96)];
    } else if (n < 288) {
        int jj = n - 192;
        v = (k < 96) ? wih[(size_t)(192 + jj) * 96 + k] : 0.f;
    } else {
        int jj = n - 288;
        v = (k < 96) ? 0.f : whh[(size_t)(192 + jj) * 96 + (k - 96)];
    }
    Wgp[idx] = f2bf(v);
}

// combined bias pack: bs[0..95]=bih_r+bhh_r, [96..191]=bih_z+bhh_z,
// [192..287]=bih_n, [288..383]=bhh_n
__global__ void bpack_k(const float* __restrict__ bih, const float* __restrict__ bhh,
                        float* __restrict__ bs)
{
    int j = threadIdx.x;
    if (j >= 96) return;
    bs[j]        = bih[j] + bhh[j];
    bs[96 + j]   = bih[96 + j] + bhh[96 + j];
    bs[192 + j]  = bih[192 + j];
    bs[288 + j]  = bhh[192 + j];
}

__global__ void pad_k(const float* __restrict__ x, float* __restrict__ h,
                      unsigned short* __restrict__ hbf)
{
    int idx = blockIdx.x * 256 + threadIdx.x;
    if (idx >= NN_ * HH) return;
    int n = idx / HH, j = idx % HH;
    float v = (j < 32) ? x[n * 32 + j] : 0.f;
    h[idx] = v;
    hbf[idx] = f2bf(v);
}

// --------------------------- CSR build (once per component) -----------------
__global__ void deg_k(const int* __restrict__ ei, int* __restrict__ deg)
{
    int e = blockIdx.x * 256 + threadIdx.x;
    if (e >= EE_) return;
    atomicAdd(&deg[ei[EE_ + e]], 1);
}

__global__ __launch_bounds__(SCAN_B) void scan1_k(
    const int* __restrict__ deg, int* __restrict__ rp, int* __restrict__ bsum)
{
    __shared__ int sh[SCAN_B];
    int i = blockIdx.x * SCAN_B + threadIdx.x;
    int v = (i < NN_) ? deg[i] : 0;
    sh[threadIdx.x] = v;
    __syncthreads();
    for (int off = 1; off < SCAN_B; off <<= 1) {
        int t = (threadIdx.x >= off) ? sh[threadIdx.x - off] : 0;
        __syncthreads();
        sh[threadIdx.x] += t;
        __syncthreads();
    }
    if (i < NN_) rp[i] = sh[threadIdx.x] - v;     // exclusive within block
    if (threadIdx.x == SCAN_B - 1) bsum[blockIdx.x] = sh[threadIdx.x];
}

__global__ __launch_bounds__(256) void scan2_k(int* __restrict__ bsum)
{
    __shared__ int sh[256];
    int v = (threadIdx.x < NB_SCAN) ? bsum[threadIdx.x] : 0;
    sh[threadIdx.x] = v;
    __syncthreads();
    for (int off = 1; off < 256; off <<= 1) {
        int t = (threadIdx.x >= off) ? sh[threadIdx.x - off] : 0;
        __syncthreads();
        sh[threadIdx.x] += t;
        __syncthreads();
    }
    if (threadIdx.x < NB_SCAN) bsum[threadIdx.x] = sh[threadIdx.x] - v;  // exclusive
}

__global__ void scan3_k(int* __restrict__ rp, const int* __restrict__ bsum,
                        int* __restrict__ cur)
{
    int i = blockIdx.x * 256 + threadIdx.x;
    if (i < NN_) {
        int r = rp[i] + bsum[i / SCAN_B];
        rp[i] = r;
        cur[i] = r;
    }
    if (i == 0) rp[NN_] = EE_;
}

// srcs stores BYTE offsets into the bf16 hbf rows (s * 192).
__global__ void fill_k(const int* __restrict__ ei, int* __restrict__ cur,
                       int* __restrict__ srcs)
{
    int e = blockIdx.x * 256 + threadIdx.x;
    if (e >= EE_) return;
    int s = ei[e];
    int d = ei[EE_ + e];
    int pos = atomicAdd(&cur[d], 1);
    srcs[pos] = s * 192;
}

// batch row pointers: batch[] is sorted, detect segment boundaries.
__global__ void brp_k(const int* __restrict__ bat, int* __restrict__ rpb)
{
    int i = blockIdx.x * 256 + threadIdx.x;
    if (i >= NN_) return;
    int b = bat[i];
    if (i == 0) {
        for (int q = 0; q <= b; q++) rpb[q] = 0;
    } else {
        int p = bat[i - 1];
        for (int q = p + 1; q <= b; q++) rpb[q] = i;
    }
    if (i == NN_ - 1) {
        for (int q = b + 1; q <= BB; q++) rpb[q] = NN_;
    }
}

// ---------------------------------------------------------------------------
// Phase A: aggbf[n] = sum over in-edges of hbf[src]  (bf16 out, fp32 acc).
// Lane (quad,lc): node lc of the tile, feature slice ks*32 + quad*8 .. +8.
// Isolates the random-gather cost in its own dispatch.
// ---------------------------------------------------------------------------
__global__ __launch_bounds__(128) void agg_k(
    const int* __restrict__ rp, const int* __restrict__ srcs,
    const unsigned short* __restrict__ hbf,
    unsigned short* __restrict__ aggbf)
{
    int tid  = threadIdx.x;
    int wave = tid >> 6;
    int lane = tid & 63;
    int quad = lane >> 4;
    int lc   = lane & 15;
    int nT0  = blockIdx.x * 4 + wave * 2;

    const char* gbase = (const char*)hbf + quad * 16;

    #pragma unroll
    for (int t = 0; t < 2; t++) {
        int node = (nT0 + t) * 16 + lc;
        f2v ag2[12];
        #pragma unroll
        for (int i = 0; i < 12; i++) ag2[i] = (f2v){0.f, 0.f};
        int e = rp[node], e1 = rp[node + 1];
        for (; e < e1; e++) {
            const char* r = gbase + srcs[e];
            uint4 u0 = *(const uint4*)r;
            uint4 u1 = *(const uint4*)(r + 64);
            uint4 u2 = *(const uint4*)(r + 128);
            acc_row_(ag2, u0, 0); acc_row_(ag2, u1, 1); acc_row_(ag2, u2, 2);
        }
        // pack to bf16 and store 3x16B at aggbf[node*96 + ks*32 + quad*8]
        #pragma unroll
        for (int ks = 0; ks < 3; ks++) {
            unsigned q0 = (unsigned)f2bf(ag2[ks * 4 + 0][0]) | ((unsigned)f2bf(ag2[ks * 4 + 0][1]) << 16);
            unsigned q1 = (unsigned)f2bf(ag2[ks * 4 + 1][0]) | ((unsigned)f2bf(ag2[ks * 4 + 1][1]) << 16);
            unsigned q2 = (unsigned)f2bf(ag2[ks * 4 + 2][0]) | ((unsigned)f2bf(ag2[ks * 4 + 2][1]) << 16);
            unsigned q3 = (unsigned)f2bf(ag2[ks * 4 + 3][0]) | ((unsigned)f2bf(ag2[ks * 4 + 3][1]) << 16);
            *(uint4*)(aggbf + (size_t)node * 96 + ks * 32 + quad * 8) =
                make_uint4(q0, q1, q2, q3);
        }
    }
}

// ---------------------------------------------------------------------------
// Phase B: GRU update, fully streaming (no cross-node reads -> in-place h/hbf).
//   Stage 1: agg = aggbf @ W[l]  (weight-stationary MFMA) -> wave-local LDS
//            transpose (D-layout -> B-operand layout), bf16
//   Stage 2: load agg frags (LDS) + own-row h frags (hbf)
//   Stage 3: G = [agg|h] @ Wg, lane-local GRUCell epilogue, write h + hbf.
// ---------------------------------------------------------------------------
__global__ __launch_bounds__(128) void gru_k(
    const unsigned short* __restrict__ aggbf,
    const unsigned short* __restrict__ Wp,   // this layer: [6][3][64][8]
    const unsigned short* __restrict__ Wgp,  // [24][6][64][8]
    const float* __restrict__ bs,
    float* __restrict__ h,
    unsigned short* __restrict__ hbf)
{
    __shared__ unsigned short as_[2][32][104];   // 13,312 B; [wave][node][feat+pad]
    int tid  = threadIdx.x;
    int wave = tid >> 6;
    int lane = tid & 63;
    int quad = lane >> 4;
    int lc   = lane & 15;
    int nT0  = blockIdx.x * 4 + wave * 2;

    // coalesced fragment loads: gathered messages + own-row h
    s8v hg[2][3], dh[2][3];
    #pragma unroll
    for (int t = 0; t < 2; t++) {
        int node = (nT0 + t) * 16 + lc;
        #pragma unroll
        for (int ks = 0; ks < 3; ks++) {
            hg[t][ks] = *(const s8v*)(aggbf + (size_t)node * 96 + ks * 32 + quad * 8);
            dh[t][ks] = *(const s8v*)(hbf   + (size_t)node * 96 + ks * 32 + quad * 8);
        }
    }

    // ---- Stage 1: agg = hagg @ W -> LDS transpose (bf16) ----
    for (int jb = 0; jb < 6; jb++) {
        f4v a1[2] = {};
        #pragma unroll
        for (int ks = 0; ks < 3; ks++) {
            s8v w = *(const s8v*)(Wp + ((size_t)(jb * 3 + ks) * 64 + lane) * 8);
            a1[0] = __builtin_amdgcn_mfma_f32_16x16x32_bf16(w, hg[0][ks], a1[0], 0, 0, 0);
            a1[1] = __builtin_amdgcn_mfma_f32_16x16x32_bf16(w, hg[1][ks], a1[1], 0, 0, 0);
        }
        #pragma unroll
        for (int t = 0; t < 2; t++) {
            unsigned short o0 = f2bf(a1[t][0]), o1 = f2bf(a1[t][1]);
            unsigned short o2 = f2bf(a1[t][2]), o3 = f2bf(a1[t][3]);
            *(uint2*)&as_[wave][t * 16 + lc][jb * 16 + quad * 4] =
                make_uint2((unsigned)o0 | ((unsigned)o1 << 16),
                           (unsigned)o2 | ((unsigned)o3 << 16));
        }
    }

    // ---- Stage 2: data fragments for the G-GEMM ----
    s8v d[2][6];
    #pragma unroll
    for (int t = 0; t < 2; t++) {
        #pragma unroll
        for (int ks = 0; ks < 3; ks++)
            d[t][ks] = *(const s8v*)&as_[wave][t * 16 + lc][ks * 32 + quad * 8];
        #pragma unroll
        for (int ks = 0; ks < 3; ks++)
            d[t][3 + ks] = dh[t][ks];
    }

    // ---- Stage 3: G-GEMM + GRUCell epilogue ----
    for (int jb = 0; jb < 6; jb++) {
        float4 hold[2];
        #pragma unroll
        for (int t = 0; t < 2; t++)
            hold[t] = *(const float4*)(h + (size_t)((nT0 + t) * 16 + lc) * 96 + jb * 16 + quad * 4);
        f4v acc[2][4] = {};
        #pragma unroll
        for (int g = 0; g < 4; g++) {
            const unsigned short* wb = Wgp + (size_t)(jb * 4 + g) * 6 * 64 * 8;
            #pragma unroll
            for (int ks = 0; ks < 6; ks++) {
                s8v w = *(const s8v*)(wb + ((size_t)ks * 64 + lane) * 8);
                acc[0][g] = __builtin_amdgcn_mfma_f32_16x16x32_bf16(w, d[0][ks], acc[0][g], 0, 0, 0);
                acc[1][g] = __builtin_amdgcn_mfma_f32_16x16x32_bf16(w, d[1][ks], acc[1][g], 0, 0, 0);
            }
        }
        const float* bp = bs + jb * 16 + quad * 4;
        float4 br  = *(const float4*)(bp);
        float4 bz  = *(const float4*)(bp + 96);
        float4 bin = *(const float4*)(bp + 192);
        float4 bhn = *(const float4*)(bp + 288);
        float brv[4]  = {br.x, br.y, br.z, br.w};
        float bzv[4]  = {bz.x, bz.y, bz.z, bz.w};
        float binv[4] = {bin.x, bin.y, bin.z, bin.w};
        float bhnv[4] = {bhn.x, bhn.y, bhn.z, bhn.w};
        #pragma unroll
        for (int t = 0; t < 2; t++) {
            int node = (nT0 + t) * 16 + lc;
            float hv[4] = {hold[t].x, hold[t].y, hold[t].z, hold[t].w};
            float out[4];
            #pragma unroll
            for (int i = 0; i < 4; i++) {
                float rg = sigmoidf_(acc[t][0][i] + brv[i]);
                float zg = sigmoidf_(acc[t][1][i] + bzv[i]);
                float nn = tanhf_(acc[t][2][i] + binv[i] + rg * (acc[t][3][i] + bhnv[i]));
                out[i] = (1.f - zg) * nn + zg * hv[i];
            }
            float* hp = h + (size_t)node * 96 + jb * 16 + quad * 4;
            *(float4*)hp = make_float4(out[0], out[1], out[2], out[3]);
            unsigned short q0 = f2bf(out[0]), q1 = f2bf(out[1]);
            unsigned short q2 = f2bf(out[2]), q3 = f2bf(out[3]);
            *(uint2*)(hbf + (size_t)node * 96 + jb * 16 + quad * 4) =
                make_uint2((unsigned)q0 | ((unsigned)q1 << 16),
                           (unsigned)q2 | ((unsigned)q3 << 16));
        }
    }
}

// ---------------------------------------------------------------------------
// Mean pool via sorted-batch segments: one block per graph, no atomics.
// ---------------------------------------------------------------------------
__global__ __launch_bounds__(128) void pool_csr_k(
    const float* __restrict__ h, const int* __restrict__ rpb, float* __restrict__ g)
{
    int b = blockIdx.x;
    int j = threadIdx.x;
    if (j >= 96) return;
    int n0 = rpb[b], n1 = rpb[b + 1];
    float s = 0.f;
    for (int n = n0; n < n1; n++) s += fmaxf(h[(size_t)n * 96 + j], 0.f);
    float c = (float)(n1 - n0);
    g[(size_t)b * 96 + j] = s / fmaxf(c, 1.f);
}

__global__ void feat_k(const float* __restrict__ g1, const float* __restrict__ g2,
                       const float* __restrict__ g3, float* __restrict__ feat)
{
    int idx = blockIdx.x * 256 + threadIdx.x;
    if (idx >= BB * HH) return;
    int b = idx / HH, j = idx % HH;
    float a = g1[idx], bb = g2[idx], c = g3[idx];
    float* f = feat + (size_t)b * 384;
    f[j]       = a;
    f[96 + j]  = bb;
    f[192 + j] = c;
    f[288 + j] = a * bb * c;
}

// ---------------------------------------------------------------------------
// MLP GEMM: C[M,N] = relu(bf16(A[M,K]) @ Bp + bias).
// ---------------------------------------------------------------------------
__global__ __launch_bounds__(256) void gemm_mlp_mfma(
    const float* __restrict__ A, const unsigned short* __restrict__ Bp,
    const float* __restrict__ bias, float* __restrict__ C,
    int K, int N, int doRelu)
{
    int wave = threadIdx.x >> 6;
    int lane = threadIdx.x & 63;
    int quad = lane >> 4;
    int lc   = lane & 15;
    int rowA = blockIdx.y * 64 + wave * 16 + lc;
    int colb = blockIdx.x * 128;

    f4v acc[8] = {};
    for (int ks = 0; ks < K / 32; ks++) {
        s8v a = load_bf8(A + (size_t)rowA * K + ks * 32 + quad * 8);
        #pragma unroll
        for (int t = 0; t < 8; t++) {
            int n = colb + t * 16 + lc;
            s8v b = *(const s8v*)(Bp + ((size_t)(ks * N + n) * 4 + quad) * 8);
            acc[t] = __builtin_amdgcn_mfma_f32_16x16x32_bf16(a, b, acc[t], 0, 0, 0);
        }
    }
    int rowD = blockIdx.y * 64 + wave * 16 + quad * 4;
    #pragma unroll
    for (int t = 0; t < 8; t++) {
        int n = colb + t * 16 + lc;
        float bv = bias[n];
        #pragma unroll
        for (int r = 0; r < 4; r++) {
            float v = acc[t][r] + bv;
            if (doRelu) v = fmaxf(v, 0.f);
            C[(size_t)(rowD + r) * N + n] = v;
        }
    }
}

// fc3: one wave per graph, shuffle reduction.
__global__ __launch_bounds__(256) void fc3_k(const float* __restrict__ t2,
                                             const float* __restrict__ w,
                                             const float* __restrict__ bias,
                                             float* __restrict__ out)
{
    int wave = threadIdx.x >> 6;
    int lane = threadIdx.x & 63;
    int b = blockIdx.x * 4 + wave;
    const float* row = t2 + (size_t)b * 384;
    float a0 = 0.f, a1 = 0.f, a2 = 0.f;
    #pragma unroll
    for (int kk = 0; kk < 6; kk++) {
        int k = kk * 64 + lane;
        float x = row[k];
        a0 += x * w[k * 3 + 0];
        a1 += x * w[k * 3 + 1];
        a2 += x * w[k * 3 + 2];
    }
    #pragma unroll
    for (int off = 32; off > 0; off >>= 1) {
        a0 += __shfl_down(a0, off);
        a1 += __shfl_down(a1, off);
        a2 += __shfl_down(a2, off);
    }
    if (lane == 0) {
        out[b * 3 + 0] = a0 + bias[0];
        out[b * 3 + 1] = a1 + bias[1];
        out[b * 3 + 2] = a2 + bias[2];
    }
}

extern "C" void kernel_launch(void* const* d_in, const int* in_sizes, int n_in,
                              void* d_out, int out_size, void* d_ws, size_t ws_size,
                              hipStream_t stream)
{
    // Workspace (floats). Total ~41.4M f ≈ 166 MB (237 MB proven safe).
    float* ws    = (float*)d_ws;
    float* h     = ws;                               // 19,200,000
    float* hbfF  = h + (size_t)NN_ * HH;             //  9,600,000 (19.2M bf16)
    float* aggF  = hbfF + (size_t)NN_ * HH / 2;      //  9,600,000 (19.2M bf16)
    float* wpF   = aggF + (size_t)NN_ * HH / 2;      //     27,648
    float* wgpF  = wpF + 27648;                      //     36,864
    float* fc1pF = wgpF + 36864;                     //    294,912 (589,824 bf16)
    float* fc2pF = fc1pF + 294912;                   //    294,912
    float* g3    = fc2pF + 294912;                   //  1,179,648
    int*   rp    = (int*)(g3 + 3 * (size_t)BB * HH); //    200,064 ints
    int*   srcs  = rp + 200064;                      //    400,000 ints
    int*   deg   = srcs + 400000;                    //    200,000 ints
    int*   cur   = deg + 200000;                     //    200,000 ints
    int*   bsum  = cur + 200000;                     //        256 ints
    int*   rpb   = bsum + 256;                       //      4,097 ints
    float* bs    = (float*)(rpb + 4097) + 1;         //        384 f (16B-aligned region)

    unsigned short* hbf  = (unsigned short*)hbfF;
    unsigned short* agg  = (unsigned short*)aggF;
    unsigned short* Wp   = (unsigned short*)wpF;
    unsigned short* Wgp  = (unsigned short*)wgpF;
    unsigned short* fc1p = (unsigned short*)fc1pF;
    unsigned short* fc2p = (unsigned short*)fc2pF;

    // MLP temps alias h (dead after pooling)
    float* feat = h;
    float* t1   = h + 2 * 1024 * 1024;
    float* t2   = h + 9 * 1024 * 1024;

    for (int c = 0; c < 3; c++) {
        const float* x   = (const float*)d_in[c * 8 + 0];
        const int*   ei  = (const int*)  d_in[c * 8 + 1];
        const int*   bat = (const int*)  d_in[c * 8 + 2];
        const float* W   = (const float*)d_in[c * 8 + 3];
        const float* wih = (const float*)d_in[c * 8 + 4];
        const float* whh = (const float*)d_in[c * 8 + 5];
        const float* bih = (const float*)d_in[c * 8 + 6];
        const float* bhh = (const float*)d_in[c * 8 + 7];

        // CSR build (once per component, reused for all 6 layers)
        hipMemsetAsync(deg, 0, NN_ * sizeof(int), stream);
        deg_k<<<cdiv(EE_, 256), 256, 0, stream>>>(ei, deg);
        scan1_k<<<NB_SCAN, SCAN_B, 0, stream>>>(deg, rp, bsum);
        scan2_k<<<1, 256, 0, stream>>>(bsum);
        scan3_k<<<cdiv(NN_, 256), 256, 0, stream>>>(rp, bsum, cur);
        fill_k<<<cdiv(EE_, 256), 256, 0, stream>>>(ei, cur, srcs);
        brp_k<<<cdiv(NN_, 256), 256, 0, stream>>>(bat, rpb);

        packWp_k<<<cdiv(LL * 6 * 3 * 64 * 8, 256), 256, 0, stream>>>(W, Wp);
        packWgp_k<<<cdiv(24 * 6 * 64 * 8, 256), 256, 0, stream>>>(wih, whh, Wgp);
        bpack_k<<<1, 128, 0, stream>>>(bih, bhh, bs);
        pad_k<<<cdiv(NN_ * HH, 256), 256, 0, stream>>>(x, h, hbf);

        for (int l = 0; l < LL; l++) {
            agg_k<<<NN_ / 64, 128, 0, stream>>>(rp, srcs, hbf, agg);
            gru_k<<<NN_ / 64, 128, 0, stream>>>(
                agg, Wp + (size_t)l * 9216, Wgp, bs, h, hbf);
        }

        pool_csr_k<<<BB, 128, 0, stream>>>(h, rpb, g3 + (size_t)c * BB * HH);
    }

    const float* fc1_w = (const float*)d_in[24];
    const float* fc1_b = (const float*)d_in[25];
    const float* fc2_w = (const float*)d_in[26];
    const float* fc2_b = (const float*)d_in[27];
    const float* fc3_w = (const float*)d_in[28];
    const float* fc3_b = (const float*)d_in[29];

    packB_k<<<cdiv(384 * 1536, 256), 256, 0, stream>>>(fc1_w, fc1p, 384, 1536);
    packB_k<<<cdiv(1536 * 384, 256), 256, 0, stream>>>(fc2_w, fc2p, 1536, 384);

    feat_k<<<cdiv(BB * HH, 256), 256, 0, stream>>>(
        g3, g3 + (size_t)BB * HH, g3 + 2 * (size_t)BB * HH, feat);
    gemm_mlp_mfma<<<dim3(1536 / 128, BB / 64), 256, 0, stream>>>(
        feat, fc1p, fc1_b, t1, 384, 1536, 1);
    gemm_mlp_mfma<<<dim3(384 / 128, BB / 64), 256, 0, stream>>>(
        t1, fc2p, fc2_b, t2, 1536, 384, 1);
    fc3_k<<<BB / 4, 256, 0, stream>>>(t2, fc3_w, fc3_b, (float*)d_out);
}

// Round 5
// 2822.474 us; speedup vs baseline: 1.4974x; 1.3914x over previous
//
#include <hip/hip_runtime.h>
#include <math.h>

#define NN_ 200000
#define EE_ 400000
#define HH  96
#define LL  6
#define BB  4096
#define NT_ 12500     // node tiles of 16
#define SCAN_B 1024
#define NB_SCAN 196   // cdiv(200000, 1024)

typedef short s8v __attribute__((ext_vector_type(8)));
typedef float f4v __attribute__((ext_vector_type(4)));
typedef float f2v __attribute__((ext_vector_type(2)));

static inline int cdiv(int a, int b) { return (a + b - 1) / b; }

__device__ __forceinline__ float sigmoidf_(float x) { return 1.0f / (1.0f + __expf(-x)); }
__device__ __forceinline__ float tanhf_(float x) { return 1.0f - 2.0f / (__expf(2.0f * x) + 1.0f); }
__device__ __forceinline__ unsigned short f2bf(float x) {
    unsigned u = __float_as_uint(x);
    unsigned r = u + 0x7FFF + ((u >> 16) & 1);   // RNE
    return (unsigned short)(r >> 16);
}
__device__ __forceinline__ float bf2f(unsigned short u) {
    return __uint_as_float(((unsigned)u) << 16);
}
// load 8 consecutive fp32 and convert to a bf16x8 MFMA fragment (in-register)
__device__ __forceinline__ s8v load_bf8(const float* __restrict__ p) {
    float4 v0 = *(const float4*)p;
    float4 v1 = *(const float4*)(p + 4);
    s8v r;
    r[0] = (short)f2bf(v0.x); r[1] = (short)f2bf(v0.y);
    r[2] = (short)f2bf(v0.z); r[3] = (short)f2bf(v0.w);
    r[4] = (short)f2bf(v1.x); r[5] = (short)f2bf(v1.y);
    r[6] = (short)f2bf(v1.z); r[7] = (short)f2bf(v1.w);
    return r;
}

// bf16-pair accumulate: u holds 2 bf16; low elem -> a[0], high elem -> a[1]
__device__ __forceinline__ void accu_(f2v& a, unsigned u) {
    a[0] += __uint_as_float(u << 16);
    a[1] += __uint_as_float(u & 0xFFFF0000u);
}
__device__ __forceinline__ void acc_row_(f2v* ag2, const uint4& u, int ks) {
    accu_(ag2[ks * 4 + 0], u.x); accu_(ag2[ks * 4 + 1], u.y);
    accu_(ag2[ks * 4 + 2], u.z); accu_(ag2[ks * 4 + 3], u.w);
}

// ---------------------------------------------------------------------------
// MLP weight pack (B-operand fragment order, read from global):
// Bp[((k>>5)*N + n)*32 + ((k>>3)&3)*8 + (k&7)] = bf16(B[k*N + n])
// ---------------------------------------------------------------------------
__global__ void packB_k(const float* __restrict__ B, unsigned short* __restrict__ Bp,
                        int K, int N)
{
    int idx = blockIdx.x * 256 + threadIdx.x;
    if (idx >= K * N) return;
    int k = idx / N, n = idx % N;
    Bp[(((size_t)(k >> 5) * N + n) * 4 + ((k >> 3) & 3)) * 8 + (k & 7)] = f2bf(B[idx]);
}

// ---------------------------------------------------------------------------
// Wp pack, weight-stationary A-operand order:
// offset = (((l*6 + jb)*3 + ks)*64 + lane)*8 + j
//   holds  W[l][k = ks*32 + (lane>>4)*8 + j][n = jb*16 + (lane&15)]
// ---------------------------------------------------------------------------
__global__ void packWp_k(const float* __restrict__ W, unsigned short* __restrict__ Wp)
{
    int idx = blockIdx.x * 256 + threadIdx.x;
    if (idx >= LL * 6 * 3 * 64 * 8) return;
    int j    = idx & 7;
    int lane = (idx >> 3) & 63;
    int rest = idx >> 9;
    int ks = rest % 3;
    int jb = (rest / 3) % 6;
    int l  = rest / 18;
    int quad = lane >> 4, lc = lane & 15;
    int k = ks * 32 + quad * 8 + j;
    int n = jb * 16 + lc;
    Wp[idx] = f2bf(W[(size_t)l * 9216 + (size_t)k * 96 + n]);
}

// ---------------------------------------------------------------------------
// Wgc pack: COMPACT gate weights [6 jb][18 ksb][64 lane][8 j]  (zeros removed)
//   ksb 0..5   -> g=0 (r), ks=ksb      (full K: agg then h)
//   ksb 6..11  -> g=1 (z), ks=ksb-6
//   ksb 12..14 -> g=2 (i_n), ks=ksb-12 (k<96: agg side only)
//   ksb 15..17 -> g=3 (h_n), ks=ksb-12 -> 3..5 (k>=96: h side only)
// value at k = ks*32 + quad*8 + j, n = g*96 + jb*16 + lc
// ---------------------------------------------------------------------------
__global__ void packWgc_k(const float* __restrict__ wih, const float* __restrict__ whh,
                          unsigned short* __restrict__ Wgc)
{
    int idx = blockIdx.x * 256 + threadIdx.x;
    if (idx >= 6 * 18 * 64 * 8) return;
    int j    = idx & 7;
    int lane = (idx >> 3) & 63;
    int rest = idx >> 9;          // < 108
    int ksb = rest % 18;
    int jb  = rest / 18;
    int quad = lane >> 4, lc = lane & 15;
    int g, ks;
    if (ksb < 6)       { g = 0; ks = ksb; }
    else if (ksb < 12) { g = 1; ks = ksb - 6; }
    else if (ksb < 15) { g = 2; ks = ksb - 12; }
    else               { g = 3; ks = ksb - 12; }   // 3..5
    int k = ks * 32 + quad * 8 + j;
    int n = g * 96 + jb * 16 + lc;
    float v;
    if (n < 192) {
        v = (k < 96) ? wih[(size_t)n * 96 + k] : whh[(size_t)n * 96 + (k - 96)];
    } else if (n < 288) {
        int jj = n - 192;
        v = wih[(size_t)(192 + jj) * 96 + k];          // g=2: k<96 guaranteed
    } else {
        int jj = n - 288;
        v = whh[(size_t)(192 + jj) * 96 + (k - 96)];   // g=3: k>=96 guaranteed
    }
    Wgc[idx] = f2bf(v);
}

// combined bias pack: bs[0..95]=bih_r+bhh_r, [96..191]=bih_z+bhh_z,
// [192..287]=bih_n, [288..383]=bhh_n
__global__ void bpack_k(const float* __restrict__ bih, const float* __restrict__ bhh,
                        float* __restrict__ bs)
{
    int j = threadIdx.x;
    if (j >= 96) return;
    bs[j]        = bih[j] + bhh[j];
    bs[96 + j]   = bih[96 + j] + bhh[96 + j];
    bs[192 + j]  = bih[192 + j];
    bs[288 + j]  = bhh[192 + j];
}

__global__ void pad_k(const float* __restrict__ x, float* __restrict__ h,
                      unsigned short* __restrict__ hbf)
{
    int idx = blockIdx.x * 256 + threadIdx.x;
    if (idx >= NN_ * HH) return;
    int n = idx / HH, j = idx % HH;
    float v = (j < 32) ? x[n * 32 + j] : 0.f;
    h[idx] = v;
    hbf[idx] = f2bf(v);
}

// --------------------------- CSR build (once per component) -----------------
__global__ void deg_k(const int* __restrict__ ei, int* __restrict__ deg)
{
    int e = blockIdx.x * 256 + threadIdx.x;
    if (e >= EE_) return;
    atomicAdd(&deg[ei[EE_ + e]], 1);
}

__global__ __launch_bounds__(SCAN_B) void scan1_k(
    const int* __restrict__ deg, int* __restrict__ rp, int* __restrict__ bsum)
{
    __shared__ int sh[SCAN_B];
    int i = blockIdx.x * SCAN_B + threadIdx.x;
    int v = (i < NN_) ? deg[i] : 0;
    sh[threadIdx.x] = v;
    __syncthreads();
    for (int off = 1; off < SCAN_B; off <<= 1) {
        int t = (threadIdx.x >= off) ? sh[threadIdx.x - off] : 0;
        __syncthreads();
        sh[threadIdx.x] += t;
        __syncthreads();
    }
    if (i < NN_) rp[i] = sh[threadIdx.x] - v;     // exclusive within block
    if (threadIdx.x == SCAN_B - 1) bsum[blockIdx.x] = sh[threadIdx.x];
}

__global__ __launch_bounds__(256) void scan2_k(int* __restrict__ bsum)
{
    __shared__ int sh[256];
    int v = (threadIdx.x < NB_SCAN) ? bsum[threadIdx.x] : 0;
    sh[threadIdx.x] = v;
    __syncthreads();
    for (int off = 1; off < 256; off <<= 1) {
        int t = (threadIdx.x >= off) ? sh[threadIdx.x - off] : 0;
        __syncthreads();
        sh[threadIdx.x] += t;
        __syncthreads();
    }
    if (threadIdx.x < NB_SCAN) bsum[threadIdx.x] = sh[threadIdx.x] - v;  // exclusive
}

__global__ void scan3_k(int* __restrict__ rp, const int* __restrict__ bsum,
                        int* __restrict__ cur)
{
    int i = blockIdx.x * 256 + threadIdx.x;
    if (i < NN_) {
        int r = rp[i] + bsum[i / SCAN_B];
        rp[i] = r;
        cur[i] = r;
    }
    if (i == 0) rp[NN_] = EE_;
}

// srcs stores BYTE offsets into the bf16 hbf rows (s * 192).
__global__ void fill_k(const int* __restrict__ ei, int* __restrict__ cur,
                       int* __restrict__ srcs)
{
    int e = blockIdx.x * 256 + threadIdx.x;
    if (e >= EE_) return;
    int s = ei[e];
    int d = ei[EE_ + e];
    int pos = atomicAdd(&cur[d], 1);
    srcs[pos] = s * 192;
}

// batch row pointers: batch[] is sorted, detect segment boundaries.
__global__ void brp_k(const int* __restrict__ bat, int* __restrict__ rpb)
{
    int i = blockIdx.x * 256 + threadIdx.x;
    if (i >= NN_) return;
    int b = bat[i];
    if (i == 0) {
        for (int q = 0; q <= b; q++) rpb[q] = 0;
    } else {
        int p = bat[i - 1];
        for (int q = p + 1; q <= b; q++) rpb[q] = i;
    }
    if (i == NN_ - 1) {
        for (int q = b + 1; q <= BB; q++) rpb[q] = NN_;
    }
}

// ---------------------------------------------------------------------------
// Phase A: aggbf[n] = sum over in-edges of hbf[src]  (bf16 out, fp32 acc).
// ---------------------------------------------------------------------------
__global__ __launch_bounds__(128) void agg_k(
    const int* __restrict__ rp, const int* __restrict__ srcs,
    const unsigned short* __restrict__ hbf,
    unsigned short* __restrict__ aggbf)
{
    int tid  = threadIdx.x;
    int wave = tid >> 6;
    int lane = tid & 63;
    int quad = lane >> 4;
    int lc   = lane & 15;
    int nT0  = blockIdx.x * 4 + wave * 2;

    const char* gbase = (const char*)hbf + quad * 16;

    #pragma unroll
    for (int t = 0; t < 2; t++) {
        int node = (nT0 + t) * 16 + lc;
        f2v ag2[12];
        #pragma unroll
        for (int i = 0; i < 12; i++) ag2[i] = (f2v){0.f, 0.f};
        int e = rp[node], e1 = rp[node + 1];
        for (; e < e1; e++) {
            const char* r = gbase + srcs[e];
            uint4 u0 = *(const uint4*)r;
            uint4 u1 = *(const uint4*)(r + 64);
            uint4 u2 = *(const uint4*)(r + 128);
            acc_row_(ag2, u0, 0); acc_row_(ag2, u1, 1); acc_row_(ag2, u2, 2);
        }
        #pragma unroll
        for (int ks = 0; ks < 3; ks++) {
            unsigned q0 = (unsigned)f2bf(ag2[ks * 4 + 0][0]) | ((unsigned)f2bf(ag2[ks * 4 + 0][1]) << 16);
            unsigned q1 = (unsigned)f2bf(ag2[ks * 4 + 1][0]) | ((unsigned)f2bf(ag2[ks * 4 + 1][1]) << 16);
            unsigned q2 = (unsigned)f2bf(ag2[ks * 4 + 2][0]) | ((unsigned)f2bf(ag2[ks * 4 + 2][1]) << 16);
            unsigned q3 = (unsigned)f2bf(ag2[ks * 4 + 3][0]) | ((unsigned)f2bf(ag2[ks * 4 + 3][1]) << 16);
            *(uint4*)(aggbf + (size_t)node * 96 + ks * 32 + quad * 8) =
                make_uint4(q0, q1, q2, q3);
        }
    }
}

// ---------------------------------------------------------------------------
// Phase B v2: GRU update with block-cooperative LDS weight staging.
// 512 thr (8 waves), block owns 256 nodes, 1 block/CU (LDS 129,024 B).
//   - Wgc (compact, 110,592 B) staged once per block -> ds_read weights.
//   - Stage 1 fused with per-32-feat as_ round-trip (18,432 B buffer).
//   - Stage 3: 18 ks-blocks/jb (zero-MFMAs eliminated: 216 vs 288).
// ---------------------------------------------------------------------------
__global__ __launch_bounds__(512, 2) void gru_k(
    const unsigned short* __restrict__ aggbf,
    const unsigned short* __restrict__ Wp,    // this layer: [6][3][64][8] (global)
    const unsigned short* __restrict__ Wgc,   // compact [6][18][64][8]
    const float* __restrict__ bs,
    float* __restrict__ h,
    unsigned short* __restrict__ hbf)
{
    __shared__ unsigned short lw[55296];          // 110,592 B compact gate weights
    __shared__ unsigned short as_[8][32][36];     //  18,432 B transpose buffer
    int tid = threadIdx.x;

    // ---- stage Wgc -> LDS (coalesced 16B) ----
    {
        const uint4* src = (const uint4*)Wgc;
        uint4* dst = (uint4*)lw;
        #pragma unroll
        for (int it = 0; it < 14; it++) {
            int i = it * 512 + tid;
            if (i < 6912) dst[i] = src[i];
        }
    }
    __syncthreads();

    int wave = tid >> 6;
    int lane = tid & 63;
    int quad = lane >> 4;
    int lc   = lane & 15;
    int nT0  = blockIdx.x * 16 + wave * 2;

    bool val[2];
    val[0] = (nT0 + 0) < NT_;
    val[1] = (nT0 + 1) < NT_;

    s8v z8;
    #pragma unroll
    for (int q = 0; q < 8; q++) z8[q] = 0;

    // coalesced fragment loads: gathered messages + own-row h (bf16)
    s8v hg[2][3], dh[2][3];
    #pragma unroll
    for (int t = 0; t < 2; t++) {
        int node = (nT0 + t) * 16 + lc;
        #pragma unroll
        for (int ks = 0; ks < 3; ks++) {
            if (val[t]) {
                hg[t][ks] = *(const s8v*)(aggbf + (size_t)node * 96 + ks * 32 + quad * 8);
                dh[t][ks] = *(const s8v*)(hbf   + (size_t)node * 96 + ks * 32 + quad * 8);
            } else {
                hg[t][ks] = z8;
                dh[t][ks] = z8;
            }
        }
    }

    // ---- Stage 1: agg@W fused with wave-local as_ transpose (per 32 feats) ----
    s8v d[2][6];
    #pragma unroll
    for (int kb = 0; kb < 3; kb++) {
        #pragma unroll
        for (int jj = 0; jj < 2; jj++) {
            int jb = kb * 2 + jj;
            f4v a1[2] = {};
            #pragma unroll
            for (int ks = 0; ks < 3; ks++) {
                s8v w = *(const s8v*)(Wp + ((size_t)(jb * 3 + ks) * 64 + lane) * 8);
                a1[0] = __builtin_amdgcn_mfma_f32_16x16x32_bf16(w, hg[0][ks], a1[0], 0, 0, 0);
                a1[1] = __builtin_amdgcn_mfma_f32_16x16x32_bf16(w, hg[1][ks], a1[1], 0, 0, 0);
            }
            #pragma unroll
            for (int t = 0; t < 2; t++) {
                unsigned short o0 = f2bf(a1[t][0]), o1 = f2bf(a1[t][1]);
                unsigned short o2 = f2bf(a1[t][2]), o3 = f2bf(a1[t][3]);
                *(uint2*)&as_[wave][t * 16 + lc][jj * 16 + quad * 4] =
                    make_uint2((unsigned)o0 | ((unsigned)o1 << 16),
                               (unsigned)o2 | ((unsigned)o3 << 16));
            }
        }
        #pragma unroll
        for (int t = 0; t < 2; t++)
            d[t][kb] = *(const s8v*)&as_[wave][t * 16 + lc][quad * 8];
    }
    #pragma unroll
    for (int t = 0; t < 2; t++) {
        d[t][3] = dh[t][0]; d[t][4] = dh[t][1]; d[t][5] = dh[t][2];
    }

    // ---- Stage 3: gate GEMM (LDS weights) + GRUCell epilogue ----
    for (int jb = 0; jb < 6; jb++) {
        float4 hold[2];
        #pragma unroll
        for (int t = 0; t < 2; t++) {
            if (val[t])
                hold[t] = *(const float4*)(h + (size_t)((nT0 + t) * 16 + lc) * 96 + jb * 16 + quad * 4);
            else
                hold[t] = make_float4(0.f, 0.f, 0.f, 0.f);
        }
        f4v acc[2][4] = {};
        const unsigned short* wj = lw + (size_t)jb * 18 * 512 + (size_t)lane * 8;
        // g = 0 (r): full K
        #pragma unroll
        for (int ks = 0; ks < 6; ks++) {
            s8v w = *(const s8v*)(wj + ks * 512);
            acc[0][0] = __builtin_amdgcn_mfma_f32_16x16x32_bf16(w, d[0][ks], acc[0][0], 0, 0, 0);
            acc[1][0] = __builtin_amdgcn_mfma_f32_16x16x32_bf16(w, d[1][ks], acc[1][0], 0, 0, 0);
        }
        // g = 1 (z): full K
        #pragma unroll
        for (int ks = 0; ks < 6; ks++) {
            s8v w = *(const s8v*)(wj + (6 + ks) * 512);
            acc[0][1] = __builtin_amdgcn_mfma_f32_16x16x32_bf16(w, d[0][ks], acc[0][1], 0, 0, 0);
            acc[1][1] = __builtin_amdgcn_mfma_f32_16x16x32_bf16(w, d[1][ks], acc[1][1], 0, 0, 0);
        }
        // g = 2 (i_n, agg side ks 0..2) and g = 3 (h_n, h side ks 3..5)
        #pragma unroll
        for (int ks = 0; ks < 6; ks++) {
            s8v w = *(const s8v*)(wj + (12 + ks) * 512);
            int g = (ks < 3) ? 2 : 3;
            acc[0][g] = __builtin_amdgcn_mfma_f32_16x16x32_bf16(w, d[0][ks], acc[0][g], 0, 0, 0);
            acc[1][g] = __builtin_amdgcn_mfma_f32_16x16x32_bf16(w, d[1][ks], acc[1][g], 0, 0, 0);
        }
        const float* bp = bs + jb * 16 + quad * 4;
        float4 br  = *(const float4*)(bp);
        float4 bz  = *(const float4*)(bp + 96);
        float4 bin = *(const float4*)(bp + 192);
        float4 bhn = *(const float4*)(bp + 288);
        float brv[4]  = {br.x, br.y, br.z, br.w};
        float bzv[4]  = {bz.x, bz.y, bz.z, bz.w};
        float binv[4] = {bin.x, bin.y, bin.z, bin.w};
        float bhnv[4] = {bhn.x, bhn.y, bhn.z, bhn.w};
        #pragma unroll
        for (int t = 0; t < 2; t++) {
            if (!val[t]) continue;
            int node = (nT0 + t) * 16 + lc;
            float hv[4] = {hold[t].x, hold[t].y, hold[t].z, hold[t].w};
            float out[4];
            #pragma unroll
            for (int i = 0; i < 4; i++) {
                float rg = sigmoidf_(acc[t][0][i] + brv[i]);
                float zg = sigmoidf_(acc[t][1][i] + bzv[i]);
                float nn = tanhf_(acc[t][2][i] + binv[i] + rg * (acc[t][3][i] + bhnv[i]));
                out[i] = (1.f - zg) * nn + zg * hv[i];
            }
            float* hp = h + (size_t)node * 96 + jb * 16 + quad * 4;
            *(float4*)hp = make_float4(out[0], out[1], out[2], out[3]);
            unsigned short q0 = f2bf(out[0]), q1 = f2bf(out[1]);
            unsigned short q2 = f2bf(out[2]), q3 = f2bf(out[3]);
            *(uint2*)(hbf + (size_t)node * 96 + jb * 16 + quad * 4) =
                make_uint2((unsigned)q0 | ((unsigned)q1 << 16),
                           (unsigned)q2 | ((unsigned)q3 << 16));
        }
    }
}

// ---------------------------------------------------------------------------
// Mean pool via sorted-batch segments: one block per graph, no atomics.
// ---------------------------------------------------------------------------
__global__ __launch_bounds__(128) void pool_csr_k(
    const float* __restrict__ h, const int* __restrict__ rpb, float* __restrict__ g)
{
    int b = blockIdx.x;
    int j = threadIdx.x;
    if (j >= 96) return;
    int n0 = rpb[b], n1 = rpb[b + 1];
    float s = 0.f;
    for (int n = n0; n < n1; n++) s += fmaxf(h[(size_t)n * 96 + j], 0.f);
    float c = (float)(n1 - n0);
    g[(size_t)b * 96 + j] = s / fmaxf(c, 1.f);
}

__global__ void feat_k(const float* __restrict__ g1, const float* __restrict__ g2,
                       const float* __restrict__ g3, float* __restrict__ feat)
{
    int idx = blockIdx.x * 256 + threadIdx.x;
    if (idx >= BB * HH) return;
    int b = idx / HH, j = idx % HH;
    float a = g1[idx], bb = g2[idx], c = g3[idx];
    float* f = feat + (size_t)b * 384;
    f[j]       = a;
    f[96 + j]  = bb;
    f[192 + j] = c;
    f[288 + j] = a * bb * c;
}

// ---------------------------------------------------------------------------
// MLP GEMM: C[M,N] = relu(bf16(A[M,K]) @ Bp + bias).
// ---------------------------------------------------------------------------
__global__ __launch_bounds__(256) void gemm_mlp_mfma(
    const float* __restrict__ A, const unsigned short* __restrict__ Bp,
    const float* __restrict__ bias, float* __restrict__ C,
    int K, int N, int doRelu)
{
    int wave = threadIdx.x >> 6;
    int lane = threadIdx.x & 63;
    int quad = lane >> 4;
    int lc   = lane & 15;
    int rowA = blockIdx.y * 64 + wave * 16 + lc;
    int colb = blockIdx.x * 128;

    f4v acc[8] = {};
    for (int ks = 0; ks < K / 32; ks++) {
        s8v a = load_bf8(A + (size_t)rowA * K + ks * 32 + quad * 8);
        #pragma unroll
        for (int t = 0; t < 8; t++) {
            int n = colb + t * 16 + lc;
            s8v b = *(const s8v*)(Bp + ((size_t)(ks * N + n) * 4 + quad) * 8);
            acc[t] = __builtin_amdgcn_mfma_f32_16x16x32_bf16(a, b, acc[t], 0, 0, 0);
        }
    }
    int rowD = blockIdx.y * 64 + wave * 16 + quad * 4;
    #pragma unroll
    for (int t = 0; t < 8; t++) {
        int n = colb + t * 16 + lc;
        float bv = bias[n];
        #pragma unroll
        for (int r = 0; r < 4; r++) {
            float v = acc[t][r] + bv;
            if (doRelu) v = fmaxf(v, 0.f);
            C[(size_t)(rowD + r) * N + n] = v;
        }
    }
}

// fc3: one wave per graph, shuffle reduction.
__global__ __launch_bounds__(256) void fc3_k(const float* __restrict__ t2,
                                             const float* __restrict__ w,
                                             const float* __restrict__ bias,
                                             float* __restrict__ out)
{
    int wave = threadIdx.x >> 6;
    int lane = threadIdx.x & 63;
    int b = blockIdx.x * 4 + wave;
    const float* row = t2 + (size_t)b * 384;
    float a0 = 0.f, a1 = 0.f, a2 = 0.f;
    #pragma unroll
    for (int kk = 0; kk < 6; kk++) {
        int k = kk * 64 + lane;
        float x = row[k];
        a0 += x * w[k * 3 + 0];
        a1 += x * w[k * 3 + 1];
        a2 += x * w[k * 3 + 2];
    }
    #pragma unroll
    for (int off = 32; off > 0; off >>= 1) {
        a0 += __shfl_down(a0, off);
        a1 += __shfl_down(a1, off);
        a2 += __shfl_down(a2, off);
    }
    if (lane == 0) {
        out[b * 3 + 0] = a0 + bias[0];
        out[b * 3 + 1] = a1 + bias[1];
        out[b * 3 + 2] = a2 + bias[2];
    }
}

extern "C" void kernel_launch(void* const* d_in, const int* in_sizes, int n_in,
                              void* d_out, int out_size, void* d_ws, size_t ws_size,
                              hipStream_t stream)
{
    // Workspace (floats). Total ~41.4M f ≈ 166 MB (237 MB proven safe).
    float* ws    = (float*)d_ws;
    float* h     = ws;                               // 19,200,000
    float* hbfF  = h + (size_t)NN_ * HH;             //  9,600,000 (19.2M bf16)
    float* aggF  = hbfF + (size_t)NN_ * HH / 2;      //  9,600,000 (19.2M bf16)
    float* wpF   = aggF + (size_t)NN_ * HH / 2;      //     27,648
    float* wgpF  = wpF + 27648;                      //     36,864 (compact uses 27,648)
    float* fc1pF = wgpF + 36864;                     //    294,912 (589,824 bf16)
    float* fc2pF = fc1pF + 294912;                   //    294,912
    float* g3    = fc2pF + 294912;                   //  1,179,648
    int*   rp    = (int*)(g3 + 3 * (size_t)BB * HH); //    200,064 ints
    int*   srcs  = rp + 200064;                      //    400,000 ints
    int*   deg   = srcs + 400000;                    //    200,000 ints
    int*   cur   = deg + 200000;                     //    200,000 ints
    int*   bsum  = cur + 200000;                     //        256 ints
    int*   rpb   = bsum + 256;                       //      4,097 ints
    float* bs    = (float*)(rpb + 4097) + 1;         //        384 f (16B-aligned region)

    unsigned short* hbf  = (unsigned short*)hbfF;
    unsigned short* agg  = (unsigned short*)aggF;
    unsigned short* Wp   = (unsigned short*)wpF;
    unsigned short* Wgc  = (unsigned short*)wgpF;
    unsigned short* fc1p = (unsigned short*)fc1pF;
    unsigned short* fc2p = (unsigned short*)fc2pF;

    // MLP temps alias h (dead after pooling)
    float* feat = h;
    float* t1   = h + 2 * 1024 * 1024;
    float* t2   = h + 9 * 1024 * 1024;

    for (int c = 0; c < 3; c++) {
        const float* x   = (const float*)d_in[c * 8 + 0];
        const int*   ei  = (const int*)  d_in[c * 8 + 1];
        const int*   bat = (const int*)  d_in[c * 8 + 2];
        const float* W   = (const float*)d_in[c * 8 + 3];
        const float* wih = (const float*)d_in[c * 8 + 4];
        const float* whh = (const float*)d_in[c * 8 + 5];
        const float* bih = (const float*)d_in[c * 8 + 6];
        const float* bhh = (const float*)d_in[c * 8 + 7];

        // CSR build (once per component, reused for all 6 layers)
        hipMemsetAsync(deg, 0, NN_ * sizeof(int), stream);
        deg_k<<<cdiv(EE_, 256), 256, 0, stream>>>(ei, deg);
        scan1_k<<<NB_SCAN, SCAN_B, 0, stream>>>(deg, rp, bsum);
        scan2_k<<<1, 256, 0, stream>>>(bsum);
        scan3_k<<<cdiv(NN_, 256), 256, 0, stream>>>(rp, bsum, cur);
        fill_k<<<cdiv(EE_, 256), 256, 0, stream>>>(ei, cur, srcs);
        brp_k<<<cdiv(NN_, 256), 256, 0, stream>>>(bat, rpb);

        packWp_k<<<cdiv(LL * 6 * 3 * 64 * 8, 256), 256, 0, stream>>>(W, Wp);
        packWgc_k<<<cdiv(6 * 18 * 64 * 8, 256), 256, 0, stream>>>(wih, whh, Wgc);
        bpack_k<<<1, 128, 0, stream>>>(bih, bhh, bs);
        pad_k<<<cdiv(NN_ * HH, 256), 256, 0, stream>>>(x, h, hbf);

        for (int l = 0; l < LL; l++) {
            agg_k<<<NN_ / 64, 128, 0, stream>>>(rp, srcs, hbf, agg);
            gru_k<<<cdiv(NT_, 16), 512, 0, stream>>>(
                agg, Wp + (size_t)l * 9216, Wgc, bs, h, hbf);
        }

        pool_csr_k<<<BB, 128, 0, stream>>>(h, rpb, g3 + (size_t)c * BB * HH);
    }

    const float* fc1_w = (const float*)d_in[24];
    const float* fc1_b = (const float*)d_in[25];
    const float* fc2_w = (const float*)d_in[26];
    const float* fc2_b = (const float*)d_in[27];
    const float* fc3_w = (const float*)d_in[28];
    const float* fc3_b = (const float*)d_in[29];

    packB_k<<<cdiv(384 * 1536, 256), 256, 0, stream>>>(fc1_w, fc1p, 384, 1536);
    packB_k<<<cdiv(1536 * 384, 256), 256, 0, stream>>>(fc2_w, fc2p, 1536, 384);

    feat_k<<<cdiv(BB * HH, 256), 256, 0, stream>>>(
        g3, g3 + (size_t)BB * HH, g3 + 2 * (size_t)BB * HH, feat);
    gemm_mlp_mfma<<<dim3(1536 / 128, BB / 64), 256, 0, stream>>>(
        feat, fc1p, fc1_b, t1, 384, 1536, 1);
    gemm_mlp_mfma<<<dim3(384 / 128, BB / 64), 256, 0, stream>>>(
        t1, fc2p, fc2_b, t2, 1536, 384, 1);
    fc3_k<<<BB / 4, 256, 0, stream>>>(t2, fc3_w, fc3_b, (float*)d_out);
}

// Round 6
// 2709.704 us; speedup vs baseline: 1.5597x; 1.0416x over previous
//
#include <hip/hip_runtime.h>
#include <math.h>

#define NN_ 200000
#define EE_ 400000
#define HH  96
#define LL  6
#define BB  4096
#define NT_ 12500     // node tiles of 16
#define SCAN_B 1024
#define NB_SCAN 196   // cdiv(200000, 1024)

typedef short s8v __attribute__((ext_vector_type(8)));
typedef float f4v __attribute__((ext_vector_type(4)));
typedef float f2v __attribute__((ext_vector_type(2)));

static inline int cdiv(int a, int b) { return (a + b - 1) / b; }

__device__ __forceinline__ float sigmoidf_(float x) { return 1.0f / (1.0f + __expf(-x)); }
__device__ __forceinline__ float tanhf_(float x) { return 1.0f - 2.0f / (__expf(2.0f * x) + 1.0f); }
__device__ __forceinline__ unsigned short f2bf(float x) {
    unsigned u = __float_as_uint(x);
    unsigned r = u + 0x7FFF + ((u >> 16) & 1);   // RNE
    return (unsigned short)(r >> 16);
}
__device__ __forceinline__ float bf2f(unsigned short u) {
    return __uint_as_float(((unsigned)u) << 16);
}
// load 8 consecutive fp32 and convert to a bf16x8 MFMA fragment (in-register)
__device__ __forceinline__ s8v load_bf8(const float* __restrict__ p) {
    float4 v0 = *(const float4*)p;
    float4 v1 = *(const float4*)(p + 4);
    s8v r;
    r[0] = (short)f2bf(v0.x); r[1] = (short)f2bf(v0.y);
    r[2] = (short)f2bf(v0.z); r[3] = (short)f2bf(v0.w);
    r[4] = (short)f2bf(v1.x); r[5] = (short)f2bf(v1.y);
    r[6] = (short)f2bf(v1.z); r[7] = (short)f2bf(v1.w);
    return r;
}

// bf16-pair accumulate: u holds 2 bf16; low elem -> a[0], high elem -> a[1]
__device__ __forceinline__ void accu_(f2v& a, unsigned u) {
    a[0] += __uint_as_float(u << 16);
    a[1] += __uint_as_float(u & 0xFFFF0000u);
}
__device__ __forceinline__ void acc_row_(f2v* ag2, const uint4& u, int ks) {
    accu_(ag2[ks * 4 + 0], u.x); accu_(ag2[ks * 4 + 1], u.y);
    accu_(ag2[ks * 4 + 2], u.z); accu_(ag2[ks * 4 + 3], u.w);
}

// ---------------------------------------------------------------------------
// MLP weight pack (B-operand fragment order, read from global):
// Bp[((k>>5)*N + n)*32 + ((k>>3)&3)*8 + (k&7)] = bf16(B[k*N + n])
// ---------------------------------------------------------------------------
__global__ void packB_k(const float* __restrict__ B, unsigned short* __restrict__ Bp,
                        int K, int N)
{
    int idx = blockIdx.x * 256 + threadIdx.x;
    if (idx >= K * N) return;
    int k = idx / N, n = idx % N;
    Bp[(((size_t)(k >> 5) * N + n) * 4 + ((k >> 3) & 3)) * 8 + (k & 7)] = f2bf(B[idx]);
}

// ---------------------------------------------------------------------------
// Wp pack, weight-stationary A-operand order:
// offset = (((l*6 + jb)*3 + ks)*64 + lane)*8 + j
//   holds  W[l][k = ks*32 + (lane>>4)*8 + j][n = jb*16 + (lane&15)]
// ---------------------------------------------------------------------------
__global__ void packWp_k(const float* __restrict__ W, unsigned short* __restrict__ Wp)
{
    int idx = blockIdx.x * 256 + threadIdx.x;
    if (idx >= LL * 6 * 3 * 64 * 8) return;
    int j    = idx & 7;
    int lane = (idx >> 3) & 63;
    int rest = idx >> 9;
    int ks = rest % 3;
    int jb = (rest / 3) % 6;
    int l  = rest / 18;
    int quad = lane >> 4, lc = lane & 15;
    int k = ks * 32 + quad * 8 + j;
    int n = jb * 16 + lc;
    Wp[idx] = f2bf(W[(size_t)l * 9216 + (size_t)k * 96 + n]);
}

// ---------------------------------------------------------------------------
// Wgc pack: COMPACT gate weights [6 jb][18 ksb][64 lane][8 j]  (zeros removed)
//   ksb 0..5   -> g=0 (r), ks=ksb      (full K: agg then h)
//   ksb 6..11  -> g=1 (z), ks=ksb-6
//   ksb 12..14 -> g=2 (i_n), ks=ksb-12 (k<96: agg side only)
//   ksb 15..17 -> g=3 (h_n), ks=ksb-12 -> 3..5 (k>=96: h side only)
// value at k = ks*32 + quad*8 + j, n = g*96 + jb*16 + lc
// ---------------------------------------------------------------------------
__global__ void packWgc_k(const float* __restrict__ wih, const float* __restrict__ whh,
                          unsigned short* __restrict__ Wgc)
{
    int idx = blockIdx.x * 256 + threadIdx.x;
    if (idx >= 6 * 18 * 64 * 8) return;
    int j    = idx & 7;
    int lane = (idx >> 3) & 63;
    int rest = idx >> 9;          // < 108
    int ksb = rest % 18;
    int jb  = rest / 18;
    int quad = lane >> 4, lc = lane & 15;
    int g, ks;
    if (ksb < 6)       { g = 0; ks = ksb; }
    else if (ksb < 12) { g = 1; ks = ksb - 6; }
    else if (ksb < 15) { g = 2; ks = ksb - 12; }
    else               { g = 3; ks = ksb - 12; }   // 3..5
    int k = ks * 32 + quad * 8 + j;
    int n = g * 96 + jb * 16 + lc;
    float v;
    if (n < 192) {
        v = (k < 96) ? wih[(size_t)n * 96 + k] : whh[(size_t)n * 96 + (k - 96)];
    } else if (n < 288) {
        int jj = n - 192;
        v = wih[(size_t)(192 + jj) * 96 + k];          // g=2: k<96 guaranteed
    } else {
        int jj = n - 288;
        v = whh[(size_t)(192 + jj) * 96 + (k - 96)];   // g=3: k>=96 guaranteed
    }
    Wgc[idx] = f2bf(v);
}

// combined bias pack: bs[0..95]=bih_r+bhh_r, [96..191]=bih_z+bhh_z,
// [192..287]=bih_n, [288..383]=bhh_n
__global__ void bpack_k(const float* __restrict__ bih, const float* __restrict__ bhh,
                        float* __restrict__ bs)
{
    int j = threadIdx.x;
    if (j >= 96) return;
    bs[j]        = bih[j] + bhh[j];
    bs[96 + j]   = bih[96 + j] + bhh[96 + j];
    bs[192 + j]  = bih[192 + j];
    bs[288 + j]  = bhh[192 + j];
}

__global__ void pad_k(const float* __restrict__ x, float* __restrict__ h,
                      unsigned short* __restrict__ hbf)
{
    int idx = blockIdx.x * 256 + threadIdx.x;
    if (idx >= NN_ * HH) return;
    int n = idx / HH, j = idx % HH;
    float v = (j < 32) ? x[n * 32 + j] : 0.f;
    h[idx] = v;
    hbf[idx] = f2bf(v);
}

// --------------------------- CSR build (once per component) -----------------
__global__ void deg_k(const int* __restrict__ ei, int* __restrict__ deg)
{
    int e = blockIdx.x * 256 + threadIdx.x;
    if (e >= EE_) return;
    atomicAdd(&deg[ei[EE_ + e]], 1);
}

__global__ __launch_bounds__(SCAN_B) void scan1_k(
    const int* __restrict__ deg, int* __restrict__ rp, int* __restrict__ bsum)
{
    __shared__ int sh[SCAN_B];
    int i = blockIdx.x * SCAN_B + threadIdx.x;
    int v = (i < NN_) ? deg[i] : 0;
    sh[threadIdx.x] = v;
    __syncthreads();
    for (int off = 1; off < SCAN_B; off <<= 1) {
        int t = (threadIdx.x >= off) ? sh[threadIdx.x - off] : 0;
        __syncthreads();
        sh[threadIdx.x] += t;
        __syncthreads();
    }
    if (i < NN_) rp[i] = sh[threadIdx.x] - v;     // exclusive within block
    if (threadIdx.x == SCAN_B - 1) bsum[blockIdx.x] = sh[threadIdx.x];
}

__global__ __launch_bounds__(256) void scan2_k(int* __restrict__ bsum)
{
    __shared__ int sh[256];
    int v = (threadIdx.x < NB_SCAN) ? bsum[threadIdx.x] : 0;
    sh[threadIdx.x] = v;
    __syncthreads();
    for (int off = 1; off < 256; off <<= 1) {
        int t = (threadIdx.x >= off) ? sh[threadIdx.x - off] : 0;
        __syncthreads();
        sh[threadIdx.x] += t;
        __syncthreads();
    }
    if (threadIdx.x < NB_SCAN) bsum[threadIdx.x] = sh[threadIdx.x] - v;  // exclusive
}

__global__ void scan3_k(int* __restrict__ rp, const int* __restrict__ bsum,
                        int* __restrict__ cur)
{
    int i = blockIdx.x * 256 + threadIdx.x;
    if (i < NN_) {
        int r = rp[i] + bsum[i / SCAN_B];
        rp[i] = r;
        cur[i] = r;
    }
    if (i == 0) rp[NN_] = EE_;
}

// srcs stores BYTE offsets into the bf16 hbf rows (s * 192).
__global__ void fill_k(const int* __restrict__ ei, int* __restrict__ cur,
                       int* __restrict__ srcs)
{
    int e = blockIdx.x * 256 + threadIdx.x;
    if (e >= EE_) return;
    int s = ei[e];
    int d = ei[EE_ + e];
    int pos = atomicAdd(&cur[d], 1);
    srcs[pos] = s * 192;
}

// batch row pointers: batch[] is sorted, detect segment boundaries.
__global__ void brp_k(const int* __restrict__ bat, int* __restrict__ rpb)
{
    int i = blockIdx.x * 256 + threadIdx.x;
    if (i >= NN_) return;
    int b = bat[i];
    if (i == 0) {
        for (int q = 0; q <= b; q++) rpb[q] = 0;
    } else {
        int p = bat[i - 1];
        for (int q = p + 1; q <= b; q++) rpb[q] = i;
    }
    if (i == NN_ - 1) {
        for (int q = b + 1; q <= BB; q++) rpb[q] = NN_;
    }
}

// ---------------------------------------------------------------------------
// Phase A: aggbf[n] = sum over in-edges of hbf[src]  (bf16 out, fp32 acc).
// ---------------------------------------------------------------------------
__global__ __launch_bounds__(128) void agg_k(
    const int* __restrict__ rp, const int* __restrict__ srcs,
    const unsigned short* __restrict__ hbf,
    unsigned short* __restrict__ aggbf)
{
    int tid  = threadIdx.x;
    int wave = tid >> 6;
    int lane = tid & 63;
    int quad = lane >> 4;
    int lc   = lane & 15;
    int nT0  = blockIdx.x * 4 + wave * 2;

    const char* gbase = (const char*)hbf + quad * 16;

    #pragma unroll
    for (int t = 0; t < 2; t++) {
        int node = (nT0 + t) * 16 + lc;
        f2v ag2[12];
        #pragma unroll
        for (int i = 0; i < 12; i++) ag2[i] = (f2v){0.f, 0.f};
        int e = rp[node], e1 = rp[node + 1];
        for (; e < e1; e++) {
            const char* r = gbase + srcs[e];
            uint4 u0 = *(const uint4*)r;
            uint4 u1 = *(const uint4*)(r + 64);
            uint4 u2 = *(const uint4*)(r + 128);
            acc_row_(ag2, u0, 0); acc_row_(ag2, u1, 1); acc_row_(ag2, u2, 2);
        }
        #pragma unroll
        for (int ks = 0; ks < 3; ks++) {
            unsigned q0 = (unsigned)f2bf(ag2[ks * 4 + 0][0]) | ((unsigned)f2bf(ag2[ks * 4 + 0][1]) << 16);
            unsigned q1 = (unsigned)f2bf(ag2[ks * 4 + 1][0]) | ((unsigned)f2bf(ag2[ks * 4 + 1][1]) << 16);
            unsigned q2 = (unsigned)f2bf(ag2[ks * 4 + 2][0]) | ((unsigned)f2bf(ag2[ks * 4 + 2][1]) << 16);
            unsigned q3 = (unsigned)f2bf(ag2[ks * 4 + 3][0]) | ((unsigned)f2bf(ag2[ks * 4 + 3][1]) << 16);
            *(uint4*)(aggbf + (size_t)node * 96 + ks * 32 + quad * 8) =
                make_uint4(q0, q1, q2, q3);
        }
    }
}

// ---------------------------------------------------------------------------
// Phase B v3: GRU update, jb-HALF-split for 2 blocks/CU occupancy.
// 512 thr (8 waves); grid (cdiv(NT_,16), 2); blockIdx.y = half (jb 3*half..+2).
//   - lw: this half's 3 jb of compact weights (55,296 B); as_ 18,432 B
//     -> 73,728 B LDS -> 2 blocks/CU (16 waves/CU, 2x prior occupancy).
//   - Stage 1 (agg@W, full 96 cols) duplicated per half (cheap, 36 MFMA).
//   - hbf ping-pong (cross-half race would corrupt in-place hbf);
//     h fp32 stays in place (each half touches only its own 48 cols).
// ---------------------------------------------------------------------------
__global__ __launch_bounds__(512) void gru_k(
    const unsigned short* __restrict__ aggbf,
    const unsigned short* __restrict__ Wp,    // this layer: [6][3][64][8] (global)
    const unsigned short* __restrict__ Wgc,   // compact [6][18][64][8]
    const float* __restrict__ bs,
    float* __restrict__ h,
    const unsigned short* __restrict__ hbf_prev,
    unsigned short* __restrict__ hbf_next)
{
    __shared__ unsigned short lw[27648];          // 55,296 B: this half's 3 jb
    __shared__ unsigned short as_[8][32][36];     // 18,432 B transpose buffer
    int tid  = threadIdx.x;
    int half = blockIdx.y;

    // ---- stage this half's Wgc -> LDS (coalesced 16B) ----
    {
        const uint4* src = (const uint4*)Wgc + (size_t)half * 3456;
        uint4* dst = (uint4*)lw;
        #pragma unroll
        for (int it = 0; it < 7; it++) {
            int i = it * 512 + tid;
            if (i < 3456) dst[i] = src[i];
        }
    }
    __syncthreads();

    int wave = tid >> 6;
    int lane = tid & 63;
    int quad = lane >> 4;
    int lc   = lane & 15;
    int nT0  = blockIdx.x * 16 + wave * 2;

    bool val[2];
    val[0] = (nT0 + 0) < NT_;
    val[1] = (nT0 + 1) < NT_;

    s8v z8;
    #pragma unroll
    for (int q = 0; q < 8; q++) z8[q] = 0;

    // coalesced fragment loads: gathered messages + own-row h (bf16, prev)
    s8v hg[2][3], dh[2][3];
    #pragma unroll
    for (int t = 0; t < 2; t++) {
        int node = (nT0 + t) * 16 + lc;
        #pragma unroll
        for (int ks = 0; ks < 3; ks++) {
            if (val[t]) {
                hg[t][ks] = *(const s8v*)(aggbf    + (size_t)node * 96 + ks * 32 + quad * 8);
                dh[t][ks] = *(const s8v*)(hbf_prev + (size_t)node * 96 + ks * 32 + quad * 8);
            } else {
                hg[t][ks] = z8;
                dh[t][ks] = z8;
            }
        }
    }

    // ---- Stage 1: agg@W (ALL 96 cols) fused with wave-local as_ transpose ----
    s8v d[2][6];
    #pragma unroll
    for (int kb = 0; kb < 3; kb++) {
        #pragma unroll
        for (int jj = 0; jj < 2; jj++) {
            int jb = kb * 2 + jj;
            f4v a1[2] = {};
            #pragma unroll
            for (int ks = 0; ks < 3; ks++) {
                s8v w = *(const s8v*)(Wp + ((size_t)(jb * 3 + ks) * 64 + lane) * 8);
                a1[0] = __builtin_amdgcn_mfma_f32_16x16x32_bf16(w, hg[0][ks], a1[0], 0, 0, 0);
                a1[1] = __builtin_amdgcn_mfma_f32_16x16x32_bf16(w, hg[1][ks], a1[1], 0, 0, 0);
            }
            #pragma unroll
            for (int t = 0; t < 2; t++) {
                unsigned short o0 = f2bf(a1[t][0]), o1 = f2bf(a1[t][1]);
                unsigned short o2 = f2bf(a1[t][2]), o3 = f2bf(a1[t][3]);
                *(uint2*)&as_[wave][t * 16 + lc][jj * 16 + quad * 4] =
                    make_uint2((unsigned)o0 | ((unsigned)o1 << 16),
                               (unsigned)o2 | ((unsigned)o3 << 16));
            }
        }
        #pragma unroll
        for (int t = 0; t < 2; t++)
            d[t][kb] = *(const s8v*)&as_[wave][t * 16 + lc][quad * 8];
    }
    #pragma unroll
    for (int t = 0; t < 2; t++) {
        d[t][3] = dh[t][0]; d[t][4] = dh[t][1]; d[t][5] = dh[t][2];
    }

    // ---- Stage 3: gate GEMM (LDS weights, this half's 3 jb) + epilogue ----
    for (int jbl = 0; jbl < 3; jbl++) {
        int jb = half * 3 + jbl;
        float4 hold[2];
        #pragma unroll
        for (int t = 0; t < 2; t++) {
            if (val[t])
                hold[t] = *(const float4*)(h + (size_t)((nT0 + t) * 16 + lc) * 96 + jb * 16 + quad * 4);
            else
                hold[t] = make_float4(0.f, 0.f, 0.f, 0.f);
        }
        f4v acc[2][4] = {};
        const unsigned short* wj = lw + (size_t)jbl * 18 * 512 + (size_t)lane * 8;
        // g = 0 (r): full K
        #pragma unroll
        for (int ks = 0; ks < 6; ks++) {
            s8v w = *(const s8v*)(wj + ks * 512);
            acc[0][0] = __builtin_amdgcn_mfma_f32_16x16x32_bf16(w, d[0][ks], acc[0][0], 0, 0, 0);
            acc[1][0] = __builtin_amdgcn_mfma_f32_16x16x32_bf16(w, d[1][ks], acc[1][0], 0, 0, 0);
        }
        // g = 1 (z): full K
        #pragma unroll
        for (int ks = 0; ks < 6; ks++) {
            s8v w = *(const s8v*)(wj + (6 + ks) * 512);
            acc[0][1] = __builtin_amdgcn_mfma_f32_16x16x32_bf16(w, d[0][ks], acc[0][1], 0, 0, 0);
            acc[1][1] = __builtin_amdgcn_mfma_f32_16x16x32_bf16(w, d[1][ks], acc[1][1], 0, 0, 0);
        }
        // g = 2 (i_n, agg side ks 0..2) and g = 3 (h_n, h side ks 3..5)
        #pragma unroll
        for (int ks = 0; ks < 6; ks++) {
            s8v w = *(const s8v*)(wj + (12 + ks) * 512);
            int g = (ks < 3) ? 2 : 3;
            acc[0][g] = __builtin_amdgcn_mfma_f32_16x16x32_bf16(w, d[0][ks], acc[0][g], 0, 0, 0);
            acc[1][g] = __builtin_amdgcn_mfma_f32_16x16x32_bf16(w, d[1][ks], acc[1][g], 0, 0, 0);
        }
        const float* bp = bs + jb * 16 + quad * 4;
        float4 br  = *(const float4*)(bp);
        float4 bz  = *(const float4*)(bp + 96);
        float4 bin = *(const float4*)(bp + 192);
        float4 bhn = *(const float4*)(bp + 288);
        float brv[4]  = {br.x, br.y, br.z, br.w};
        float bzv[4]  = {bz.x, bz.y, bz.z, bz.w};
        float binv[4] = {bin.x, bin.y, bin.z, bin.w};
        float bhnv[4] = {bhn.x, bhn.y, bhn.z, bhn.w};
        #pragma unroll
        for (int t = 0; t < 2; t++) {
            if (!val[t]) continue;
            int node = (nT0 + t) * 16 + lc;
            float hv[4] = {hold[t].x, hold[t].y, hold[t].z, hold[t].w};
            float out[4];
            #pragma unroll
            for (int i = 0; i < 4; i++) {
                float rg = sigmoidf_(acc[t][0][i] + brv[i]);
                float zg = sigmoidf_(acc[t][1][i] + bzv[i]);
                float nn = tanhf_(acc[t][2][i] + binv[i] + rg * (acc[t][3][i] + bhnv[i]));
                out[i] = (1.f - zg) * nn + zg * hv[i];
            }
            float* hp = h + (size_t)node * 96 + jb * 16 + quad * 4;
            *(float4*)hp = make_float4(out[0], out[1], out[2], out[3]);
            unsigned short q0 = f2bf(out[0]), q1 = f2bf(out[1]);
            unsigned short q2 = f2bf(out[2]), q3 = f2bf(out[3]);
            *(uint2*)(hbf_next + (size_t)node * 96 + jb * 16 + quad * 4) =
                make_uint2((unsigned)q0 | ((unsigned)q1 << 16),
                           (unsigned)q2 | ((unsigned)q3 << 16));
        }
    }
}

// ---------------------------------------------------------------------------
// Mean pool via sorted-batch segments: one block per graph, no atomics.
// ---------------------------------------------------------------------------
__global__ __launch_bounds__(128) void pool_csr_k(
    const float* __restrict__ h, const int* __restrict__ rpb, float* __restrict__ g)
{
    int b = blockIdx.x;
    int j = threadIdx.x;
    if (j >= 96) return;
    int n0 = rpb[b], n1 = rpb[b + 1];
    float s = 0.f;
    for (int n = n0; n < n1; n++) s += fmaxf(h[(size_t)n * 96 + j], 0.f);
    float c = (float)(n1 - n0);
    g[(size_t)b * 96 + j] = s / fmaxf(c, 1.f);
}

__global__ void feat_k(const float* __restrict__ g1, const float* __restrict__ g2,
                       const float* __restrict__ g3, float* __restrict__ feat)
{
    int idx = blockIdx.x * 256 + threadIdx.x;
    if (idx >= BB * HH) return;
    int b = idx / HH, j = idx % HH;
    float a = g1[idx], bb = g2[idx], c = g3[idx];
    float* f = feat + (size_t)b * 384;
    f[j]       = a;
    f[96 + j]  = bb;
    f[192 + j] = c;
    f[288 + j] = a * bb * c;
}

// ---------------------------------------------------------------------------
// MLP GEMM v2: C[M,N] = relu(bf16(A[M,K]) @ Bp + bias).
// grid (N/128, M/16); 4 waves share the same 16 A-rows, each owns a 32-col
// strip -> 4-6x more blocks than v1 (latency hiding via block concurrency).
// ---------------------------------------------------------------------------
__global__ __launch_bounds__(256) void gemm_mlp_mfma(
    const float* __restrict__ A, const unsigned short* __restrict__ Bp,
    const float* __restrict__ bias, float* __restrict__ C,
    int K, int N, int doRelu)
{
    int wave = threadIdx.x >> 6;
    int lane = threadIdx.x & 63;
    int quad = lane >> 4;
    int lc   = lane & 15;
    int rowA = blockIdx.y * 16 + lc;
    int colb = blockIdx.x * 128 + wave * 32;

    f4v acc[2] = {};
    for (int ks = 0; ks < K / 32; ks++) {
        s8v a = load_bf8(A + (size_t)rowA * K + ks * 32 + quad * 8);
        #pragma unroll
        for (int t = 0; t < 2; t++) {
            int n = colb + t * 16 + lc;
            s8v b = *(const s8v*)(Bp + ((size_t)(ks * N + n) * 4 + quad) * 8);
            acc[t] = __builtin_amdgcn_mfma_f32_16x16x32_bf16(a, b, acc[t], 0, 0, 0);
        }
    }
    int rowD = blockIdx.y * 16 + quad * 4;
    #pragma unroll
    for (int t = 0; t < 2; t++) {
        int n = colb + t * 16 + lc;
        float bv = bias[n];
        #pragma unroll
        for (int r = 0; r < 4; r++) {
            float v = acc[t][r] + bv;
            if (doRelu) v = fmaxf(v, 0.f);
            C[(size_t)(rowD + r) * N + n] = v;
        }
    }
}

// fc3: one wave per graph, shuffle reduction.
__global__ __launch_bounds__(256) void fc3_k(const float* __restrict__ t2,
                                             const float* __restrict__ w,
                                             const float* __restrict__ bias,
                                             float* __restrict__ out)
{
    int wave = threadIdx.x >> 6;
    int lane = threadIdx.x & 63;
    int b = blockIdx.x * 4 + wave;
    const float* row = t2 + (size_t)b * 384;
    float a0 = 0.f, a1 = 0.f, a2 = 0.f;
    #pragma unroll
    for (int kk = 0; kk < 6; kk++) {
        int k = kk * 64 + lane;
        float x = row[k];
        a0 += x * w[k * 3 + 0];
        a1 += x * w[k * 3 + 1];
        a2 += x * w[k * 3 + 2];
    }
    #pragma unroll
    for (int off = 32; off > 0; off >>= 1) {
        a0 += __shfl_down(a0, off);
        a1 += __shfl_down(a1, off);
        a2 += __shfl_down(a2, off);
    }
    if (lane == 0) {
        out[b * 3 + 0] = a0 + bias[0];
        out[b * 3 + 1] = a1 + bias[1];
        out[b * 3 + 2] = a2 + bias[2];
    }
}

extern "C" void kernel_launch(void* const* d_in, const int* in_sizes, int n_in,
                              void* d_out, int out_size, void* d_ws, size_t ws_size,
                              hipStream_t stream)
{
    // Workspace (floats). Total ~50.1M f ≈ 200 MB (237 MB proven safe).
    float* ws    = (float*)d_ws;
    float* h     = ws;                               // 19,200,000
    float* hbfAF = h + (size_t)NN_ * HH;             //  9,600,000 (19.2M bf16)
    float* hbfBF = hbfAF + (size_t)NN_ * HH / 2;     //  9,600,000 (19.2M bf16)
    float* aggF  = hbfBF + (size_t)NN_ * HH / 2;     //  9,600,000 (19.2M bf16)
    float* wpF   = aggF + (size_t)NN_ * HH / 2;      //     27,648
    float* wgpF  = wpF + 27648;                      //     36,864 (compact uses 27,648)
    float* fc1pF = wgpF + 36864;                     //    294,912 (589,824 bf16)
    float* fc2pF = fc1pF + 294912;                   //    294,912
    float* g3    = fc2pF + 294912;                   //  1,179,648
    int*   rp    = (int*)(g3 + 3 * (size_t)BB * HH); //    200,064 ints
    int*   srcs  = rp + 200064;                      //    400,000 ints
    int*   deg   = srcs + 400000;                    //    200,000 ints
    int*   cur   = deg + 200000;                     //    200,000 ints
    int*   bsum  = cur + 200000;                     //        256 ints
    int*   rpb   = bsum + 256;                       //      4,097 ints
    float* bs    = (float*)(rpb + 4097) + 1;         //        384 f (16B-aligned region)

    unsigned short* hbfA = (unsigned short*)hbfAF;
    unsigned short* hbfB = (unsigned short*)hbfBF;
    unsigned short* agg  = (unsigned short*)aggF;
    unsigned short* Wp   = (unsigned short*)wpF;
    unsigned short* Wgc  = (unsigned short*)wgpF;
    unsigned short* fc1p = (unsigned short*)fc1pF;
    unsigned short* fc2p = (unsigned short*)fc2pF;

    // MLP temps alias h (dead after pooling)
    float* feat = h;
    float* t1   = h + 2 * 1024 * 1024;
    float* t2   = h + 9 * 1024 * 1024;

    for (int c = 0; c < 3; c++) {
        const float* x   = (const float*)d_in[c * 8 + 0];
        const int*   ei  = (const int*)  d_in[c * 8 + 1];
        const int*   bat = (const int*)  d_in[c * 8 + 2];
        const float* W   = (const float*)d_in[c * 8 + 3];
        const float* wih = (const float*)d_in[c * 8 + 4];
        const float* whh = (const float*)d_in[c * 8 + 5];
        const float* bih = (const float*)d_in[c * 8 + 6];
        const float* bhh = (const float*)d_in[c * 8 + 7];

        // CSR build (once per component, reused for all 6 layers)
        hipMemsetAsync(deg, 0, NN_ * sizeof(int), stream);
        deg_k<<<cdiv(EE_, 256), 256, 0, stream>>>(ei, deg);
        scan1_k<<<NB_SCAN, SCAN_B, 0, stream>>>(deg, rp, bsum);
        scan2_k<<<1, 256, 0, stream>>>(bsum);
        scan3_k<<<cdiv(NN_, 256), 256, 0, stream>>>(rp, bsum, cur);
        fill_k<<<cdiv(EE_, 256), 256, 0, stream>>>(ei, cur, srcs);
        brp_k<<<cdiv(NN_, 256), 256, 0, stream>>>(bat, rpb);

        packWp_k<<<cdiv(LL * 6 * 3 * 64 * 8, 256), 256, 0, stream>>>(W, Wp);
        packWgc_k<<<cdiv(6 * 18 * 64 * 8, 256), 256, 0, stream>>>(wih, whh, Wgc);
        bpack_k<<<1, 128, 0, stream>>>(bih, bhh, bs);
        pad_k<<<cdiv(NN_ * HH, 256), 256, 0, stream>>>(x, h, hbfA);

        unsigned short* pb[2] = {hbfA, hbfB};
        for (int l = 0; l < LL; l++) {
            agg_k<<<NN_ / 64, 128, 0, stream>>>(rp, srcs, pb[l & 1], agg);
            gru_k<<<dim3(cdiv(NT_, 16), 2), 512, 0, stream>>>(
                agg, Wp + (size_t)l * 9216, Wgc, bs, h, pb[l & 1], pb[(l + 1) & 1]);
        }

        pool_csr_k<<<BB, 128, 0, stream>>>(h, rpb, g3 + (size_t)c * BB * HH);
    }

    const float* fc1_w = (const float*)d_in[24];
    const float* fc1_b = (const float*)d_in[25];
    const float* fc2_w = (const float*)d_in[26];
    const float* fc2_b = (const float*)d_in[27];
    const float* fc3_w = (const float*)d_in[28];
    const float* fc3_b = (const float*)d_in[29];

    packB_k<<<cdiv(384 * 1536, 256), 256, 0, stream>>>(fc1_w, fc1p, 384, 1536);
    packB_k<<<cdiv(1536 * 384, 256), 256, 0, stream>>>(fc2_w, fc2p, 1536, 384);

    feat_k<<<cdiv(BB * HH, 256), 256, 0, stream>>>(
        g3, g3 + (size_t)BB * HH, g3 + 2 * (size_t)BB * HH, feat);
    gemm_mlp_mfma<<<dim3(1536 / 128, BB / 16), 256, 0, stream>>>(
        feat, fc1p, fc1_b, t1, 384, 1536, 1);
    gemm_mlp_mfma<<<dim3(384 / 128, BB / 16), 256, 0, stream>>>(
        t1, fc2p, fc2_b, t2, 1536, 384, 1);
    fc3_k<<<BB / 4, 256, 0, stream>>>(t2, fc3_w, fc3_b, (float*)d_out);
}

// Round 7
// 2486.509 us; speedup vs baseline: 1.6997x; 1.0898x over previous
//
#include <hip/hip_runtime.h>
#include <math.h>

#define NN_ 200000
#define EE_ 400000
#define HH  96
#define LL  6
#define BB  4096
#define NT_ 12500     // node tiles of 16
#define SCAN_B 1024
#define NB_SCAN 196   // cdiv(200000, 1024)

typedef short s8v __attribute__((ext_vector_type(8)));
typedef float f4v __attribute__((ext_vector_type(4)));
typedef float f2v __attribute__((ext_vector_type(2)));

static inline int cdiv(int a, int b) { return (a + b - 1) / b; }

__device__ __forceinline__ float sigmoidf_(float x) { return 1.0f / (1.0f + __expf(-x)); }
__device__ __forceinline__ float tanhf_(float x) { return 1.0f - 2.0f / (__expf(2.0f * x) + 1.0f); }
__device__ __forceinline__ unsigned short f2bf(float x) {
    unsigned u = __float_as_uint(x);
    unsigned r = u + 0x7FFF + ((u >> 16) & 1);   // RNE
    return (unsigned short)(r >> 16);
}
__device__ __forceinline__ float bf2f(unsigned short u) {
    return __uint_as_float(((unsigned)u) << 16);
}
// load 8 consecutive fp32 and convert to a bf16x8 MFMA fragment (in-register)
__device__ __forceinline__ s8v load_bf8(const float* __restrict__ p) {
    float4 v0 = *(const float4*)p;
    float4 v1 = *(const float4*)(p + 4);
    s8v r;
    r[0] = (short)f2bf(v0.x); r[1] = (short)f2bf(v0.y);
    r[2] = (short)f2bf(v0.z); r[3] = (short)f2bf(v0.w);
    r[4] = (short)f2bf(v1.x); r[5] = (short)f2bf(v1.y);
    r[6] = (short)f2bf(v1.z); r[7] = (short)f2bf(v1.w);
    return r;
}

// bf16-pair accumulate: u holds 2 bf16; low elem -> a[0], high elem -> a[1]
__device__ __forceinline__ void accu_(f2v& a, unsigned u) {
    a[0] += __uint_as_float(u << 16);
    a[1] += __uint_as_float(u & 0xFFFF0000u);
}
__device__ __forceinline__ void acc_row_(f2v* ag2, const uint4& u, int ks) {
    accu_(ag2[ks * 4 + 0], u.x); accu_(ag2[ks * 4 + 1], u.y);
    accu_(ag2[ks * 4 + 2], u.z); accu_(ag2[ks * 4 + 3], u.w);
}

// ---------------------------------------------------------------------------
// MLP weight pack (B-operand fragment order, read from global):
// Bp[((k>>5)*N + n)*32 + ((k>>3)&3)*8 + (k&7)] = bf16(B[k*N + n])
// ---------------------------------------------------------------------------
__global__ void packB_k(const float* __restrict__ B, unsigned short* __restrict__ Bp,
                        int K, int N)
{
    int idx = blockIdx.x * 256 + threadIdx.x;
    if (idx >= K * N) return;
    int k = idx / N, n = idx % N;
    Bp[(((size_t)(k >> 5) * N + n) * 4 + ((k >> 3) & 3)) * 8 + (k & 7)] = f2bf(B[idx]);
}

// ---------------------------------------------------------------------------
// Wp pack, weight-stationary A-operand order:
// offset = (((l*6 + jb)*3 + ks)*64 + lane)*8 + j
//   holds  W[l][k = ks*32 + (lane>>4)*8 + j][n = jb*16 + (lane&15)]
// ---------------------------------------------------------------------------
__global__ void packWp_k(const float* __restrict__ W, unsigned short* __restrict__ Wp)
{
    int idx = blockIdx.x * 256 + threadIdx.x;
    if (idx >= LL * 6 * 3 * 64 * 8) return;
    int j    = idx & 7;
    int lane = (idx >> 3) & 63;
    int rest = idx >> 9;
    int ks = rest % 3;
    int jb = (rest / 3) % 6;
    int l  = rest / 18;
    int quad = lane >> 4, lc = lane & 15;
    int k = ks * 32 + quad * 8 + j;
    int n = jb * 16 + lc;
    Wp[idx] = f2bf(W[(size_t)l * 9216 + (size_t)k * 96 + n]);
}

// ---------------------------------------------------------------------------
// Wgc pack: COMPACT gate weights [6 jb][18 ksb][64 lane][8 j]  (zeros removed)
//   ksb 0..5   -> g=0 (r), ks=ksb      (full K: agg then h)
//   ksb 6..11  -> g=1 (z), ks=ksb-6
//   ksb 12..14 -> g=2 (i_n), ks=ksb-12 (k<96: agg side only)
//   ksb 15..17 -> g=3 (h_n), ks=ksb-12 -> 3..5 (k>=96: h side only)
// value at k = ks*32 + quad*8 + j, n = g*96 + jb*16 + lc
// ---------------------------------------------------------------------------
__global__ void packWgc_k(const float* __restrict__ wih, const float* __restrict__ whh,
                          unsigned short* __restrict__ Wgc)
{
    int idx = blockIdx.x * 256 + threadIdx.x;
    if (idx >= 6 * 18 * 64 * 8) return;
    int j    = idx & 7;
    int lane = (idx >> 3) & 63;
    int rest = idx >> 9;          // < 108
    int ksb = rest % 18;
    int jb  = rest / 18;
    int quad = lane >> 4, lc = lane & 15;
    int g, ks;
    if (ksb < 6)       { g = 0; ks = ksb; }
    else if (ksb < 12) { g = 1; ks = ksb - 6; }
    else if (ksb < 15) { g = 2; ks = ksb - 12; }
    else               { g = 3; ks = ksb - 12; }   // 3..5
    int k = ks * 32 + quad * 8 + j;
    int n = g * 96 + jb * 16 + lc;
    float v;
    if (n < 192) {
        v = (k < 96) ? wih[(size_t)n * 96 + k] : whh[(size_t)n * 96 + (k - 96)];
    } else if (n < 288) {
        int jj = n - 192;
        v = wih[(size_t)(192 + jj) * 96 + k];          // g=2: k<96 guaranteed
    } else {
        int jj = n - 288;
        v = whh[(size_t)(192 + jj) * 96 + (k - 96)];   // g=3: k>=96 guaranteed
    }
    Wgc[idx] = f2bf(v);
}

// combined bias pack: bs[0..95]=bih_r+bhh_r, [96..191]=bih_z+bhh_z,
// [192..287]=bih_n, [288..383]=bhh_n
__global__ void bpack_k(const float* __restrict__ bih, const float* __restrict__ bhh,
                        float* __restrict__ bs)
{
    int j = threadIdx.x;
    if (j >= 96) return;
    bs[j]        = bih[j] + bhh[j];
    bs[96 + j]   = bih[96 + j] + bhh[96 + j];
    bs[192 + j]  = bih[192 + j];
    bs[288 + j]  = bhh[192 + j];
}

__global__ void pad_k(const float* __restrict__ x, unsigned short* __restrict__ hbf)
{
    int idx = blockIdx.x * 256 + threadIdx.x;
    if (idx >= NN_ * HH) return;
    int n = idx / HH, j = idx % HH;
    float v = (j < 32) ? x[n * 32 + j] : 0.f;
    hbf[idx] = f2bf(v);
}

// --------------------------- CSR build (once per component) -----------------
__global__ void deg_k(const int* __restrict__ ei, int* __restrict__ deg)
{
    int e = blockIdx.x * 256 + threadIdx.x;
    if (e >= EE_) return;
    atomicAdd(&deg[ei[EE_ + e]], 1);
}

__global__ __launch_bounds__(SCAN_B) void scan1_k(
    const int* __restrict__ deg, int* __restrict__ rp, int* __restrict__ bsum)
{
    __shared__ int sh[SCAN_B];
    int i = blockIdx.x * SCAN_B + threadIdx.x;
    int v = (i < NN_) ? deg[i] : 0;
    sh[threadIdx.x] = v;
    __syncthreads();
    for (int off = 1; off < SCAN_B; off <<= 1) {
        int t = (threadIdx.x >= off) ? sh[threadIdx.x - off] : 0;
        __syncthreads();
        sh[threadIdx.x] += t;
        __syncthreads();
    }
    if (i < NN_) rp[i] = sh[threadIdx.x] - v;     // exclusive within block
    if (threadIdx.x == SCAN_B - 1) bsum[blockIdx.x] = sh[threadIdx.x];
}

__global__ __launch_bounds__(256) void scan2_k(int* __restrict__ bsum)
{
    __shared__ int sh[256];
    int v = (threadIdx.x < NB_SCAN) ? bsum[threadIdx.x] : 0;
    sh[threadIdx.x] = v;
    __syncthreads();
    for (int off = 1; off < 256; off <<= 1) {
        int t = (threadIdx.x >= off) ? sh[threadIdx.x - off] : 0;
        __syncthreads();
        sh[threadIdx.x] += t;
        __syncthreads();
    }
    if (threadIdx.x < NB_SCAN) bsum[threadIdx.x] = sh[threadIdx.x] - v;  // exclusive
}

__global__ void scan3_k(int* __restrict__ rp, const int* __restrict__ bsum,
                        int* __restrict__ cur)
{
    int i = blockIdx.x * 256 + threadIdx.x;
    if (i < NN_) {
        int r = rp[i] + bsum[i / SCAN_B];
        rp[i] = r;
        cur[i] = r;
    }
    if (i == 0) rp[NN_] = EE_;
}

// srcs stores BYTE offsets into the bf16 hbf rows (s * 192).
__global__ void fill_k(const int* __restrict__ ei, int* __restrict__ cur,
                       int* __restrict__ srcs)
{
    int e = blockIdx.x * 256 + threadIdx.x;
    if (e >= EE_) return;
    int s = ei[e];
    int d = ei[EE_ + e];
    int pos = atomicAdd(&cur[d], 1);
    srcs[pos] = s * 192;
}

// batch row pointers: batch[] is sorted, detect segment boundaries.
__global__ void brp_k(const int* __restrict__ bat, int* __restrict__ rpb)
{
    int i = blockIdx.x * 256 + threadIdx.x;
    if (i >= NN_) return;
    int b = bat[i];
    if (i == 0) {
        for (int q = 0; q <= b; q++) rpb[q] = 0;
    } else {
        int p = bat[i - 1];
        for (int q = p + 1; q <= b; q++) rpb[q] = i;
    }
    if (i == NN_ - 1) {
        for (int q = b + 1; q <= BB; q++) rpb[q] = NN_;
    }
}

// ---------------------------------------------------------------------------
// Phase A: aggbf[n] = sum over in-edges of hbf[src]  (bf16 out, fp32 acc).
// ---------------------------------------------------------------------------
__global__ __launch_bounds__(128) void agg_k(
    const int* __restrict__ rp, const int* __restrict__ srcs,
    const unsigned short* __restrict__ hbf,
    unsigned short* __restrict__ aggbf)
{
    int tid  = threadIdx.x;
    int wave = tid >> 6;
    int lane = tid & 63;
    int quad = lane >> 4;
    int lc   = lane & 15;
    int nT0  = blockIdx.x * 4 + wave * 2;

    const char* gbase = (const char*)hbf + quad * 16;

    #pragma unroll
    for (int t = 0; t < 2; t++) {
        int node = (nT0 + t) * 16 + lc;
        f2v ag2[12];
        #pragma unroll
        for (int i = 0; i < 12; i++) ag2[i] = (f2v){0.f, 0.f};
        int e = rp[node], e1 = rp[node + 1];
        for (; e < e1; e++) {
            const char* r = gbase + srcs[e];
            uint4 u0 = *(const uint4*)r;
            uint4 u1 = *(const uint4*)(r + 64);
            uint4 u2 = *(const uint4*)(r + 128);
            acc_row_(ag2, u0, 0); acc_row_(ag2, u1, 1); acc_row_(ag2, u2, 2);
        }
        #pragma unroll
        for (int ks = 0; ks < 3; ks++) {
            unsigned q0 = (unsigned)f2bf(ag2[ks * 4 + 0][0]) | ((unsigned)f2bf(ag2[ks * 4 + 0][1]) << 16);
            unsigned q1 = (unsigned)f2bf(ag2[ks * 4 + 1][0]) | ((unsigned)f2bf(ag2[ks * 4 + 1][1]) << 16);
            unsigned q2 = (unsigned)f2bf(ag2[ks * 4 + 2][0]) | ((unsigned)f2bf(ag2[ks * 4 + 2][1]) << 16);
            unsigned q3 = (unsigned)f2bf(ag2[ks * 4 + 3][0]) | ((unsigned)f2bf(ag2[ks * 4 + 3][1]) << 16);
            *(uint4*)(aggbf + (size_t)node * 96 + ks * 32 + quad * 8) =
                make_uint4(q0, q1, q2, q3);
        }
    }
}

// ---------------------------------------------------------------------------
// Phase B v4: GRU update, bf16-ONLY carried state.
// 512 thr (8 waves); grid (cdiv(NT_,16), 2); blockIdx.y = half (jb 3*half..+2).
//   - lw: this half's 3 jb compact weights (55,296 B) + as_ (18,432 B)
//     -> 73,728 B LDS -> 2 blocks/CU.
//   - h_old read as bf16 from hbf_prev (uint2, L1-hot: row already loaded
//     for dh frags). fp32 h written ONLY when writeH (last layer, for pool).
//   - Per-layer HBM traffic: ~115 MB vs 273 MB with the fp32 shadow state.
// ---------------------------------------------------------------------------
__global__ __launch_bounds__(512) void gru_k(
    const unsigned short* __restrict__ aggbf,
    const unsigned short* __restrict__ Wp,    // this layer: [6][3][64][8] (global)
    const unsigned short* __restrict__ Wgc,   // compact [6][18][64][8]
    const float* __restrict__ bs,
    const unsigned short* __restrict__ hbf_prev,
    unsigned short* __restrict__ hbf_next,
    float* __restrict__ h,
    int writeH)
{
    __shared__ unsigned short lw[27648];          // 55,296 B: this half's 3 jb
    __shared__ unsigned short as_[8][32][36];     // 18,432 B transpose buffer
    int tid  = threadIdx.x;
    int half = blockIdx.y;

    // ---- stage this half's Wgc -> LDS (coalesced 16B) ----
    {
        const uint4* src = (const uint4*)Wgc + (size_t)half * 3456;
        uint4* dst = (uint4*)lw;
        #pragma unroll
        for (int it = 0; it < 7; it++) {
            int i = it * 512 + tid;
            if (i < 3456) dst[i] = src[i];
        }
    }
    __syncthreads();

    int wave = tid >> 6;
    int lane = tid & 63;
    int quad = lane >> 4;
    int lc   = lane & 15;
    int nT0  = blockIdx.x * 16 + wave * 2;

    bool val[2];
    val[0] = (nT0 + 0) < NT_;
    val[1] = (nT0 + 1) < NT_;

    s8v z8;
    #pragma unroll
    for (int q = 0; q < 8; q++) z8[q] = 0;

    // coalesced fragment loads: gathered messages + own-row h (bf16, prev)
    s8v hg[2][3], dh[2][3];
    #pragma unroll
    for (int t = 0; t < 2; t++) {
        int node = (nT0 + t) * 16 + lc;
        #pragma unroll
        for (int ks = 0; ks < 3; ks++) {
            if (val[t]) {
                hg[t][ks] = *(const s8v*)(aggbf    + (size_t)node * 96 + ks * 32 + quad * 8);
                dh[t][ks] = *(const s8v*)(hbf_prev + (size_t)node * 96 + ks * 32 + quad * 8);
            } else {
                hg[t][ks] = z8;
                dh[t][ks] = z8;
            }
        }
    }

    // ---- Stage 1: agg@W (ALL 96 cols) fused with wave-local as_ transpose ----
    s8v d[2][6];
    #pragma unroll
    for (int kb = 0; kb < 3; kb++) {
        #pragma unroll
        for (int jj = 0; jj < 2; jj++) {
            int jb = kb * 2 + jj;
            f4v a1[2] = {};
            #pragma unroll
            for (int ks = 0; ks < 3; ks++) {
                s8v w = *(const s8v*)(Wp + ((size_t)(jb * 3 + ks) * 64 + lane) * 8);
                a1[0] = __builtin_amdgcn_mfma_f32_16x16x32_bf16(w, hg[0][ks], a1[0], 0, 0, 0);
                a1[1] = __builtin_amdgcn_mfma_f32_16x16x32_bf16(w, hg[1][ks], a1[1], 0, 0, 0);
            }
            #pragma unroll
            for (int t = 0; t < 2; t++) {
                unsigned short o0 = f2bf(a1[t][0]), o1 = f2bf(a1[t][1]);
                unsigned short o2 = f2bf(a1[t][2]), o3 = f2bf(a1[t][3]);
                *(uint2*)&as_[wave][t * 16 + lc][jj * 16 + quad * 4] =
                    make_uint2((unsigned)o0 | ((unsigned)o1 << 16),
                               (unsigned)o2 | ((unsigned)o3 << 16));
            }
        }
        #pragma unroll
        for (int t = 0; t < 2; t++)
            d[t][kb] = *(const s8v*)&as_[wave][t * 16 + lc][quad * 8];
    }
    #pragma unroll
    for (int t = 0; t < 2; t++) {
        d[t][3] = dh[t][0]; d[t][4] = dh[t][1]; d[t][5] = dh[t][2];
    }

    // ---- Stage 3: gate GEMM (LDS weights, this half's 3 jb) + epilogue ----
    for (int jbl = 0; jbl < 3; jbl++) {
        int jb = half * 3 + jbl;
        // h_old (bf16) at this lane's OUTPUT position (jb*16 + quad*4): 8B,
        // L1-hot (row cached by the dh fragment loads above)
        uint2 hu[2];
        #pragma unroll
        for (int t = 0; t < 2; t++) {
            if (val[t])
                hu[t] = *(const uint2*)(hbf_prev + (size_t)((nT0 + t) * 16 + lc) * 96 + jb * 16 + quad * 4);
            else
                hu[t] = make_uint2(0u, 0u);
        }
        f4v acc[2][4] = {};
        const unsigned short* wj = lw + (size_t)jbl * 18 * 512 + (size_t)lane * 8;
        // g = 0 (r): full K
        #pragma unroll
        for (int ks = 0; ks < 6; ks++) {
            s8v w = *(const s8v*)(wj + ks * 512);
            acc[0][0] = __builtin_amdgcn_mfma_f32_16x16x32_bf16(w, d[0][ks], acc[0][0], 0, 0, 0);
            acc[1][0] = __builtin_amdgcn_mfma_f32_16x16x32_bf16(w, d[1][ks], acc[1][0], 0, 0, 0);
        }
        // g = 1 (z): full K
        #pragma unroll
        for (int ks = 0; ks < 6; ks++) {
            s8v w = *(const s8v*)(wj + (6 + ks) * 512);
            acc[0][1] = __builtin_amdgcn_mfma_f32_16x16x32_bf16(w, d[0][ks], acc[0][1], 0, 0, 0);
            acc[1][1] = __builtin_amdgcn_mfma_f32_16x16x32_bf16(w, d[1][ks], acc[1][1], 0, 0, 0);
        }
        // g = 2 (i_n, agg side ks 0..2) and g = 3 (h_n, h side ks 3..5)
        #pragma unroll
        for (int ks = 0; ks < 6; ks++) {
            s8v w = *(const s8v*)(wj + (12 + ks) * 512);
            int g = (ks < 3) ? 2 : 3;
            acc[0][g] = __builtin_amdgcn_mfma_f32_16x16x32_bf16(w, d[0][ks], acc[0][g], 0, 0, 0);
            acc[1][g] = __builtin_amdgcn_mfma_f32_16x16x32_bf16(w, d[1][ks], acc[1][g], 0, 0, 0);
        }
        const float* bp = bs + jb * 16 + quad * 4;
        float4 br  = *(const float4*)(bp);
        float4 bz  = *(const float4*)(bp + 96);
        float4 bin = *(const float4*)(bp + 192);
        float4 bhn = *(const float4*)(bp + 288);
        float brv[4]  = {br.x, br.y, br.z, br.w};
        float bzv[4]  = {bz.x, bz.y, bz.z, bz.w};
        float binv[4] = {bin.x, bin.y, bin.z, bin.w};
        float bhnv[4] = {bhn.x, bhn.y, bhn.z, bhn.w};
        #pragma unroll
        for (int t = 0; t < 2; t++) {
            if (!val[t]) continue;
            int node = (nT0 + t) * 16 + lc;
            float hv[4];
            hv[0] = bf2f((unsigned short)(hu[t].x & 0xFFFF));
            hv[1] = bf2f((unsigned short)(hu[t].x >> 16));
            hv[2] = bf2f((unsigned short)(hu[t].y & 0xFFFF));
            hv[3] = bf2f((unsigned short)(hu[t].y >> 16));
            float out[4];
            #pragma unroll
            for (int i = 0; i < 4; i++) {
                float rg = sigmoidf_(acc[t][0][i] + brv[i]);
                float zg = sigmoidf_(acc[t][1][i] + bzv[i]);
                float nn = tanhf_(acc[t][2][i] + binv[i] + rg * (acc[t][3][i] + bhnv[i]));
                out[i] = (1.f - zg) * nn + zg * hv[i];
            }
            unsigned short q0 = f2bf(out[0]), q1 = f2bf(out[1]);
            unsigned short q2 = f2bf(out[2]), q3 = f2bf(out[3]);
            *(uint2*)(hbf_next + (size_t)node * 96 + jb * 16 + quad * 4) =
                make_uint2((unsigned)q0 | ((unsigned)q1 << 16),
                           (unsigned)q2 | ((unsigned)q3 << 16));
            if (writeH) {
                float* hp = h + (size_t)node * 96 + jb * 16 + quad * 4;
                *(float4*)hp = make_float4(out[0], out[1], out[2], out[3]);
            }
        }
    }
}

// ---------------------------------------------------------------------------
// Mean pool via sorted-batch segments: one block per graph, no atomics.
// ---------------------------------------------------------------------------
__global__ __launch_bounds__(128) void pool_csr_k(
    const float* __restrict__ h, const int* __restrict__ rpb, float* __restrict__ g)
{
    int b = blockIdx.x;
    int j = threadIdx.x;
    if (j >= 96) return;
    int n0 = rpb[b], n1 = rpb[b + 1];
    float s = 0.f;
    for (int n = n0; n < n1; n++) s += fmaxf(h[(size_t)n * 96 + j], 0.f);
    float c = (float)(n1 - n0);
    g[(size_t)b * 96 + j] = s / fmaxf(c, 1.f);
}

__global__ void feat_k(const float* __restrict__ g1, const float* __restrict__ g2,
                       const float* __restrict__ g3, float* __restrict__ feat)
{
    int idx = blockIdx.x * 256 + threadIdx.x;
    if (idx >= BB * HH) return;
    int b = idx / HH, j = idx % HH;
    float a = g1[idx], bb = g2[idx], c = g3[idx];
    float* f = feat + (size_t)b * 384;
    f[j]       = a;
    f[96 + j]  = bb;
    f[192 + j] = c;
    f[288 + j] = a * bb * c;
}

// ---------------------------------------------------------------------------
// MLP GEMM v2: C[M,N] = relu(bf16(A[M,K]) @ Bp + bias).
// grid (N/128, M/16); 4 waves share the same 16 A-rows, each owns a 32-col
// strip -> high block concurrency for latency hiding.
// ---------------------------------------------------------------------------
__global__ __launch_bounds__(256) void gemm_mlp_mfma(
    const float* __restrict__ A, const unsigned short* __restrict__ Bp,
    const float* __restrict__ bias, float* __restrict__ C,
    int K, int N, int doRelu)
{
    int wave = threadIdx.x >> 6;
    int lane = threadIdx.x & 63;
    int quad = lane >> 4;
    int lc   = lane & 15;
    int rowA = blockIdx.y * 16 + lc;
    int colb = blockIdx.x * 128 + wave * 32;

    f4v acc[2] = {};
    for (int ks = 0; ks < K / 32; ks++) {
        s8v a = load_bf8(A + (size_t)rowA * K + ks * 32 + quad * 8);
        #pragma unroll
        for (int t = 0; t < 2; t++) {
            int n = colb + t * 16 + lc;
            s8v b = *(const s8v*)(Bp + ((size_t)(ks * N + n) * 4 + quad) * 8);
            acc[t] = __builtin_amdgcn_mfma_f32_16x16x32_bf16(a, b, acc[t], 0, 0, 0);
        }
    }
    int rowD = blockIdx.y * 16 + quad * 4;
    #pragma unroll
    for (int t = 0; t < 2; t++) {
        int n = colb + t * 16 + lc;
        float bv = bias[n];
        #pragma unroll
        for (int r = 0; r < 4; r++) {
            float v = acc[t][r] + bv;
            if (doRelu) v = fmaxf(v, 0.f);
            C[(size_t)(rowD + r) * N + n] = v;
        }
    }
}

// fc3: one wave per graph, shuffle reduction.
__global__ __launch_bounds__(256) void fc3_k(const float* __restrict__ t2,
                                             const float* __restrict__ w,
                                             const float* __restrict__ bias,
                                             float* __restrict__ out)
{
    int wave = threadIdx.x >> 6;
    int lane = threadIdx.x & 63;
    int b = blockIdx.x * 4 + wave;
    const float* row = t2 + (size_t)b * 384;
    float a0 = 0.f, a1 = 0.f, a2 = 0.f;
    #pragma unroll
    for (int kk = 0; kk < 6; kk++) {
        int k = kk * 64 + lane;
        float x = row[k];
        a0 += x * w[k * 3 + 0];
        a1 += x * w[k * 3 + 1];
        a2 += x * w[k * 3 + 2];
    }
    #pragma unroll
    for (int off = 32; off > 0; off >>= 1) {
        a0 += __shfl_down(a0, off);
        a1 += __shfl_down(a1, off);
        a2 += __shfl_down(a2, off);
    }
    if (lane == 0) {
        out[b * 3 + 0] = a0 + bias[0];
        out[b * 3 + 1] = a1 + bias[1];
        out[b * 3 + 2] = a2 + bias[2];
    }
}

extern "C" void kernel_launch(void* const* d_in, const int* in_sizes, int n_in,
                              void* d_out, int out_size, void* d_ws, size_t ws_size,
                              hipStream_t stream)
{
    // Workspace (floats). Total ~50.1M f ≈ 200 MB (237 MB proven safe).
    float* ws    = (float*)d_ws;
    float* h     = ws;                               // 19,200,000 (last-layer only)
    float* hbfAF = h + (size_t)NN_ * HH;             //  9,600,000 (19.2M bf16)
    float* hbfBF = hbfAF + (size_t)NN_ * HH / 2;     //  9,600,000 (19.2M bf16)
    float* aggF  = hbfBF + (size_t)NN_ * HH / 2;     //  9,600,000 (19.2M bf16)
    float* wpF   = aggF + (size_t)NN_ * HH / 2;      //     27,648
    float* wgpF  = wpF + 27648;                      //     36,864 (compact uses 27,648)
    float* fc1pF = wgpF + 36864;                     //    294,912 (589,824 bf16)
    float* fc2pF = fc1pF + 294912;                   //    294,912
    float* g3    = fc2pF + 294912;                   //  1,179,648
    int*   rp    = (int*)(g3 + 3 * (size_t)BB * HH); //    200,064 ints
    int*   srcs  = rp + 200064;                      //    400,000 ints
    int*   deg   = srcs + 400000;                    //    200,000 ints
    int*   cur   = deg + 200000;                     //    200,000 ints
    int*   bsum  = cur + 200000;                     //        256 ints
    int*   rpb   = bsum + 256;                       //      4,097 ints
    float* bs    = (float*)(rpb + 4097) + 1;         //        384 f (16B-aligned region)

    unsigned short* hbfA = (unsigned short*)hbfAF;
    unsigned short* hbfB = (unsigned short*)hbfBF;
    unsigned short* agg  = (unsigned short*)aggF;
    unsigned short* Wp   = (unsigned short*)wpF;
    unsigned short* Wgc  = (unsigned short*)wgpF;
    unsigned short* fc1p = (unsigned short*)fc1pF;
    unsigned short* fc2p = (unsigned short*)fc2pF;

    // MLP temps alias h (dead after pooling)
    float* feat = h;
    float* t1   = h + 2 * 1024 * 1024;
    float* t2   = h + 9 * 1024 * 1024;

    for (int c = 0; c < 3; c++) {
        const float* x   = (const float*)d_in[c * 8 + 0];
        const int*   ei  = (const int*)  d_in[c * 8 + 1];
        const int*   bat = (const int*)  d_in[c * 8 + 2];
        const float* W   = (const float*)d_in[c * 8 + 3];
        const float* wih = (const float*)d_in[c * 8 + 4];
        const float* whh = (const float*)d_in[c * 8 + 5];
        const float* bih = (const float*)d_in[c * 8 + 6];
        const float* bhh = (const float*)d_in[c * 8 + 7];

        // CSR build (once per component, reused for all 6 layers)
        hipMemsetAsync(deg, 0, NN_ * sizeof(int), stream);
        deg_k<<<cdiv(EE_, 256), 256, 0, stream>>>(ei, deg);
        scan1_k<<<NB_SCAN, SCAN_B, 0, stream>>>(deg, rp, bsum);
        scan2_k<<<1, 256, 0, stream>>>(bsum);
        scan3_k<<<cdiv(NN_, 256), 256, 0, stream>>>(rp, bsum, cur);
        fill_k<<<cdiv(EE_, 256), 256, 0, stream>>>(ei, cur, srcs);
        brp_k<<<cdiv(NN_, 256), 256, 0, stream>>>(bat, rpb);

        packWp_k<<<cdiv(LL * 6 * 3 * 64 * 8, 256), 256, 0, stream>>>(W, Wp);
        packWgc_k<<<cdiv(6 * 18 * 64 * 8, 256), 256, 0, stream>>>(wih, whh, Wgc);
        bpack_k<<<1, 128, 0, stream>>>(bih, bhh, bs);
        pad_k<<<cdiv(NN_ * HH, 256), 256, 0, stream>>>(x, hbfA);

        unsigned short* pb[2] = {hbfA, hbfB};
        for (int l = 0; l < LL; l++) {
            agg_k<<<NN_ / 64, 128, 0, stream>>>(rp, srcs, pb[l & 1], agg);
            gru_k<<<dim3(cdiv(NT_, 16), 2), 512, 0, stream>>>(
                agg, Wp + (size_t)l * 9216, Wgc, bs, pb[l & 1], pb[(l + 1) & 1],
                h, (l == LL - 1) ? 1 : 0);
        }

        pool_csr_k<<<BB, 128, 0, stream>>>(h, rpb, g3 + (size_t)c * BB * HH);
    }

    const float* fc1_w = (const float*)d_in[24];
    const float* fc1_b = (const float*)d_in[25];
    const float* fc2_w = (const float*)d_in[26];
    const float* fc2_b = (const float*)d_in[27];
    const float* fc3_w = (const float*)d_in[28];
    const float* fc3_b = (const float*)d_in[29];

    packB_k<<<cdiv(384 * 1536, 256), 256, 0, stream>>>(fc1_w, fc1p, 384, 1536);
    packB_k<<<cdiv(1536 * 384, 256), 256, 0, stream>>>(fc2_w, fc2p, 1536, 384);

    feat_k<<<cdiv(BB * HH, 256), 256, 0, stream>>>(
        g3, g3 + (size_t)BB * HH, g3 + 2 * (size_t)BB * HH, feat);
    gemm_mlp_mfma<<<dim3(1536 / 128, BB / 16), 256, 0, stream>>>(
        feat, fc1p, fc1_b, t1, 384, 1536, 1);
    gemm_mlp_mfma<<<dim3(384 / 128, BB / 16), 256, 0, stream>>>(
        t1, fc2p, fc2_b, t2, 1536, 384, 1);
    fc3_k<<<BB / 4, 256, 0, stream>>>(t2, fc3_w, fc3_b, (float*)d_out);
}